// Round 15
// 659.386 us; speedup vs baseline: 4.1054x; 1.1372x over previous
//
#include <hip/hip_runtime.h>
#include <cstdint>

// ---------------- problem constants ----------------
constexpr int BATCH  = 8;
constexpr int TSEQ   = 512;
constexpr int DMODEL = 1024;
constexpr int NEXP   = 8;
constexpr int CAPE   = 640;
constexpr int NTOK   = BATCH * TSEQ;        // 4096

typedef _Float16 h16;
typedef __attribute__((ext_vector_type(8))) short bfrag;
typedef __attribute__((ext_vector_type(8))) _Float16 hfrag;
typedef __attribute__((ext_vector_type(4))) float f32x4;

__device__ __forceinline__ unsigned short f2bf(float f) {
    uint32_t u = __float_as_uint(f);
    uint32_t r = (u + 0x7FFFu + ((u >> 16) & 1u)) >> 16;   // RNE
    return (unsigned short)r;
}
__device__ __forceinline__ float bf2f(unsigned short b) {
    return __uint_as_float((uint32_t)b << 16);
}

#define GLL16(SRC, DST) __builtin_amdgcn_global_load_lds( \
    (const __attribute__((address_space(1))) void*)(SRC), \
    (__attribute__((address_space(3))) void*)(DST), 16, 0, 0)

// ---------------- LayerNorm -> f16 hi/lo ----------------
__global__ __launch_bounds__(256) void ln_hl(const float* __restrict__ in,
    const float* __restrict__ gw, const float* __restrict__ gb,
    h16* __restrict__ ohi, h16* __restrict__ olo)
{
    int row = blockIdx.x, tid = threadIdx.x;
    const float4 v = *(const float4*)(in + (size_t)row * DMODEL + tid * 4);
    float s  = v.x + v.y + v.z + v.w;
    float ss = v.x*v.x + v.y*v.y + v.z*v.z + v.w*v.w;
#pragma unroll
    for (int o = 1; o < 64; o <<= 1) { s += __shfl_xor(s, o, 64); ss += __shfl_xor(ss, o, 64); }
    __shared__ float rs[4], rss[4];
    int wid = tid >> 6, lane = tid & 63;
    if (lane == 0) { rs[wid] = s; rss[wid] = ss; }
    __syncthreads();
    s  = rs[0] + rs[1] + rs[2] + rs[3];
    ss = rss[0] + rss[1] + rss[2] + rss[3];
    float mean = s * (1.0f / DMODEL);
    float var  = ss * (1.0f / DMODEL) - mean * mean;
    float inv  = rsqrtf(var + 1e-5f);
    float4 w4 = *(const float4*)(gw + tid * 4);
    float4 b4 = *(const float4*)(gb + tid * 4);
    float o[4];
    o[0] = (v.x - mean) * inv * w4.x + b4.x;
    o[1] = (v.y - mean) * inv * w4.y + b4.y;
    o[2] = (v.z - mean) * inv * w4.z + b4.z;
    o[3] = (v.w - mean) * inv * w4.w + b4.w;
    short4 hv, lv;
#pragma unroll
    for (int j = 0; j < 4; ++j) {
        h16 hh = (h16)o[j];
        ((h16*)&hv)[j] = hh;
        ((h16*)&lv)[j] = (h16)(o[j] - (float)hh);
    }
    *(short4*)(ohi + (size_t)row * DMODEL + tid * 4) = hv;
    *(short4*)(olo + (size_t)row * DMODEL + tid * 4) = lv;
}

// ---------------- fp32 -> fp16 hi/lo split ----------------
__global__ __launch_bounds__(256) void split_f16(const float* __restrict__ in,
    h16* __restrict__ hi, h16* __restrict__ lo, int n8)
{
    int i = blockIdx.x * 256 + threadIdx.x;
    if (i >= n8) return;
    const float4* p = (const float4*)in + 2 * (size_t)i;
    float4 v0 = p[0], v1 = p[1];
    float vv[8] = {v0.x, v0.y, v0.z, v0.w, v1.x, v1.y, v1.z, v1.w};
    hfrag h, l;
#pragma unroll
    for (int j = 0; j < 8; ++j) {
        h16 hj = (h16)vv[j];
        h[j] = hj;
        l[j] = (h16)(vv[j] - (float)hj);
    }
    ((hfrag*)hi)[i] = h;
    ((hfrag*)lo)[i] = l;
}

// ---------------- fp16 split NT MFMA GEMM, BK=64 ----------------
// OMODE: 0 fp32 out, 1 fp32 out + res, 2 f16 hi/lo out
// APL: 2 = A hi/lo (3-product), 1 = A hi only (2-product)
template<int OMODE, int APL>
__global__ __launch_bounds__(256) void gemm_f16x2_nt(
    const h16* __restrict__ Ahi, const h16* __restrict__ Alo, int lda,
    const h16* __restrict__ Bhi, const h16* __restrict__ Blo, int ldb,
    const float* __restrict__ bias, const float* __restrict__ res,
    float* __restrict__ C, h16* __restrict__ Chi, h16* __restrict__ Clo,
    int K, int ldc)
{
    __shared__ h16 AhL[8192];
    __shared__ h16 AlL[APL == 2 ? 8192 : 8];
    __shared__ h16 BhL[8192], BlL[8192];
    int rowBase = blockIdx.y * 128, colBase = blockIdx.x * 128;
    int t = threadIdx.x, lane = t & 63, wid = t >> 6;
    int wr = (wid >> 1) * 64, wc = (wid & 1) * 64;
    const h16* Ah = Ahi + (size_t)rowBase * lda;
    const h16* Al = (APL == 2) ? (Alo + (size_t)rowBase * lda) : nullptr;
    const h16* Bh = Bhi + (size_t)colBase * ldb;
    const h16* Bl = Blo + (size_t)colBase * ldb;
    f32x4 acc[4][4] = {};
    int l15 = lane & 15, g = lane >> 4;

    for (int k0 = 0; k0 < K; k0 += 64) {
        __syncthreads();
#pragma unroll
        for (int cc = 0; cc < 4; ++cc) {
            int c = t + cc * 256;
            int r = c >> 3, sq = (c & 7) ^ (r & 7);
            GLL16(Ah + (size_t)r * lda + k0 + sq * 8, &AhL[c * 8]);
            if (APL == 2)
                GLL16(Al + (size_t)r * lda + k0 + sq * 8, &AlL[c * 8]);
            GLL16(Bh + (size_t)r * ldb + k0 + sq * 8, &BhL[c * 8]);
            GLL16(Bl + (size_t)r * ldb + k0 + sq * 8, &BlL[c * 8]);
        }
        __syncthreads();

#pragma unroll
        for (int kk = 0; kk < 2; ++kk) {
            hfrag bh[4], bl[4];
#pragma unroll
            for (int n = 0; n < 4; ++n) {
                int rr = wc + n * 16 + l15;
                int q = ((kk << 2) | g) ^ (rr & 7);
                bh[n] = *(const hfrag*)&BhL[rr * 64 + q * 8];
                bl[n] = *(const hfrag*)&BlL[rr * 64 + q * 8];
            }
#pragma unroll
            for (int m = 0; m < 4; ++m) {
                int rr = wr + m * 16 + l15;
                int q = ((kk << 2) | g) ^ (rr & 7);
                hfrag ah = *(const hfrag*)&AhL[rr * 64 + q * 8];
#pragma unroll
                for (int n = 0; n < 4; ++n) {
                    acc[m][n] = __builtin_amdgcn_mfma_f32_16x16x32_f16(ah, bh[n], acc[m][n], 0, 0, 0);
                    acc[m][n] = __builtin_amdgcn_mfma_f32_16x16x32_f16(ah, bl[n], acc[m][n], 0, 0, 0);
                }
                if (APL == 2) {
                    hfrag al = *(const hfrag*)&AlL[rr * 64 + q * 8];
#pragma unroll
                    for (int n = 0; n < 4; ++n)
                        acc[m][n] = __builtin_amdgcn_mfma_f32_16x16x32_f16(al, bh[n], acc[m][n], 0, 0, 0);
                }
            }
        }
    }

    int g4 = g * 4;
#pragma unroll
    for (int m = 0; m < 4; ++m) {
        int row0 = rowBase + wr + m * 16 + g4;
#pragma unroll
        for (int n = 0; n < 4; ++n) {
            int col = colBase + wc + n * 16 + l15;
            float bv = bias[col];
#pragma unroll
            for (int j = 0; j < 4; ++j) {
                float v = acc[m][n][j] + bv;
                if (OMODE == 1) v += res[(size_t)(row0 + j) * ldc + col];
                if (OMODE < 2) {
                    C[(size_t)(row0 + j) * ldc + col] = v;
                } else {
                    h16 hh = (h16)v;
                    Chi[(size_t)(row0 + j) * ldc + col] = hh;
                    Clo[(size_t)(row0 + j) * ldc + col] = (h16)(v - (float)hh);
                }
            }
        }
    }
}

// ---------------- attention QK^T (f16x2, K=64 single step) -> single f16 S ----------------
template<bool CAUSAL>
__global__ __launch_bounds__(256) void attn_qk(
    const h16* __restrict__ Qh, const h16* __restrict__ Ql, int lda,
    const h16* __restrict__ Kh, const h16* __restrict__ Kl, int ldb,
    h16* __restrict__ Sh, int zoff)
{
    int rowBase = blockIdx.y * 128, colBase = blockIdx.x * 128;
    if (CAUSAL && colBase >= rowBase + 128) return;
    __shared__ h16 AhL[8192], AlL[8192], BhL[8192], BlL[8192];
    int z = blockIdx.z;
    int bh_ = zoff + z, b = bh_ >> 4, h = bh_ & 15;
    const h16* Ah = Qh + (size_t)(b * 512 + rowBase) * lda + h * 64;
    const h16* Al = Ql + (size_t)(b * 512 + rowBase) * lda + h * 64;
    const h16* Bh = Kh + (size_t)(b * 512 + colBase) * ldb + h * 64;
    const h16* Bl = Kl + (size_t)(b * 512 + colBase) * ldb + h * 64;
    int t = threadIdx.x, lane = t & 63, wid = t >> 6;
    int wr = (wid >> 1) * 64, wc = (wid & 1) * 64;
    f32x4 acc[4][4] = {};
    int l15 = lane & 15, g = lane >> 4;

#pragma unroll
    for (int cc = 0; cc < 4; ++cc) {
        int c = t + cc * 256;
        int r = c >> 3, sq = (c & 7) ^ (r & 7);
        GLL16(Ah + (size_t)r * lda + sq * 8, &AhL[c * 8]);
        GLL16(Al + (size_t)r * lda + sq * 8, &AlL[c * 8]);
        GLL16(Bh + (size_t)r * ldb + sq * 8, &BhL[c * 8]);
        GLL16(Bl + (size_t)r * ldb + sq * 8, &BlL[c * 8]);
    }
    __syncthreads();

#pragma unroll
    for (int kk = 0; kk < 2; ++kk) {
        hfrag bh[4], bl[4];
#pragma unroll
        for (int n = 0; n < 4; ++n) {
            int rr = wc + n * 16 + l15;
            int q = ((kk << 2) | g) ^ (rr & 7);
            bh[n] = *(const hfrag*)&BhL[rr * 64 + q * 8];
            bl[n] = *(const hfrag*)&BlL[rr * 64 + q * 8];
        }
#pragma unroll
        for (int m = 0; m < 4; ++m) {
            int rr = wr + m * 16 + l15;
            int q = ((kk << 2) | g) ^ (rr & 7);
            hfrag ah = *(const hfrag*)&AhL[rr * 64 + q * 8];
            hfrag al = *(const hfrag*)&AlL[rr * 64 + q * 8];
#pragma unroll
            for (int n = 0; n < 4; ++n) {
                acc[m][n] = __builtin_amdgcn_mfma_f32_16x16x32_f16(ah, bh[n], acc[m][n], 0, 0, 0);
                acc[m][n] = __builtin_amdgcn_mfma_f32_16x16x32_f16(ah, bl[n], acc[m][n], 0, 0, 0);
                acc[m][n] = __builtin_amdgcn_mfma_f32_16x16x32_f16(al, bh[n], acc[m][n], 0, 0, 0);
            }
        }
    }

    size_t sbase = (size_t)z * 262144;
    int g4 = g * 4;
#pragma unroll
    for (int m = 0; m < 4; ++m) {
        int row0 = rowBase + wr + m * 16 + g4;
#pragma unroll
        for (int n = 0; n < 4; ++n) {
            int col = colBase + wc + n * 16 + l15;
#pragma unroll
            for (int j = 0; j < 4; ++j)
                Sh[sbase + (size_t)(row0 + j) * 512 + col] = (h16)(acc[m][n][j] * 0.125f);
        }
    }
}

// ---------------- fused softmax+PV: 512 threads, in-block K-split, f16 ctx out ----------------
template<bool CAUSAL>
__global__ __launch_bounds__(512) void attn_pv(
    const h16* __restrict__ Shg,
    const h16* __restrict__ Vh,
    h16* __restrict__ Ch, int bh0)
{
    __shared__ h16 ShL[2][4096], VhL[2][4096];
    __shared__ float red[256][16];
    __shared__ float mS[64], iS[64];
    int z = blockIdx.z, bh_ = bh0 + z;
    int rowBase = blockIdx.x * 64;
    const h16* Sa = Shg + (size_t)z * 262144 + (size_t)rowBase * 512;
    const h16* Va = Vh + (size_t)z * 32768;
    int t = threadIdx.x;
    int wv = t >> 6, lane = t & 63;
    int g2 = wv >> 2, wid = wv & 3, tl = t & 255;
    int l15 = lane & 15, g = lane >> 4;

    {
        int tr = t >> 3, tq = t & 7;
        int limit = CAUSAL ? (rowBase + tr + 1) : 512;
        float m = -1e30f, l = 0.f;
        const h16* rh = Sa + (size_t)tr * 512;
        for (int c = 0; c < 8; ++c) {
            int col0 = tq * 8 + c * 64;
            if (col0 >= limit) break;
            hfrag hv = *(const hfrag*)(rh + col0);
            float s[8]; float cm = -1e30f;
#pragma unroll
            for (int j = 0; j < 8; ++j) {
                float sv = (float)hv[j];
                s[j] = (col0 + j < limit) ? sv : -1e30f;
                cm = fmaxf(cm, s[j]);
            }
            if (cm > m) { l *= __expf(m - cm); m = cm; }
#pragma unroll
            for (int j = 0; j < 8; ++j) l += __expf(s[j] - m);
        }
#pragma unroll
        for (int o = 1; o < 8; o <<= 1) {
            float mo = __shfl_xor(m, o, 64);
            float lo2 = __shfl_xor(l, o, 64);
            float mc = fmaxf(m, mo);
            l = l * __expf(m - mc) + lo2 * __expf(mo - mc);
            m = mc;
        }
        if (tq == 0) { mS[tr] = m; iS[tr] = 1.0f / l; }
    }
    __syncthreads();

    int arow = wid * 16 + l15;
    float am = mS[arow], ai = iS[arow];
    int alim = CAUSAL ? (rowBase + arow + 1) : 512;
    int kend = CAUSAL ? (rowBase + 64) : 512;
    int nck = kend >> 6;
    f32x4 acc[4] = {};

    for (int ci = 0; ci < nck; ci += 2) {
        int myck = ci + g2;
        bool act = myck < nck;
        int k0 = myck << 6;
        __syncthreads();
        if (act) {
#pragma unroll
            for (int cc = 0; cc < 2; ++cc) {
                int c = tl + cc * 256;
                int r = c >> 3, sq = (c & 7) ^ (r & 7);
                GLL16(Sa + (size_t)r * 512 + k0 + sq * 8, &ShL[g2][c * 8]);
                GLL16(Va + (size_t)r * 512 + k0 + sq * 8, &VhL[g2][c * 8]);
            }
        }
        __syncthreads();
        if (act) {
#pragma unroll
            for (int kk = 0; kk < 2; ++kk) {
                int chunk = (kk << 2) | g;
                int aq = chunk ^ (arow & 7);
                hfrag sh_ = *(const hfrag*)&ShL[g2][arow * 64 + aq * 8];
                int cbase = k0 + chunk * 8;
                hfrag ph, pl;
#pragma unroll
                for (int j = 0; j < 8; ++j) {
                    float p = __expf((float)sh_[j] - am) * ai;
                    p = (cbase + j < alim) ? p : 0.f;
                    h16 hh = (h16)p;
                    ph[j] = hh;
                    pl[j] = (h16)(p - (float)hh);
                }
#pragma unroll
                for (int n = 0; n < 4; ++n) {
                    int brow = n * 16 + l15;
                    int bq = chunk ^ (brow & 7);
                    hfrag bh = *(const hfrag*)&VhL[g2][brow * 64 + bq * 8];
                    acc[n] = __builtin_amdgcn_mfma_f32_16x16x32_f16(ph, bh, acc[n], 0, 0, 0);
                    acc[n] = __builtin_amdgcn_mfma_f32_16x16x32_f16(pl, bh, acc[n], 0, 0, 0);
                }
            }
        }
    }

    __syncthreads();
    if (g2 == 1) {
#pragma unroll
        for (int n = 0; n < 4; ++n)
#pragma unroll
            for (int j = 0; j < 4; ++j) red[tl][n * 4 + j] = acc[n][j];
    }
    __syncthreads();
    if (g2 == 0) {
        int brow = (bh_ >> 4) * 512 + rowBase + wid * 16 + g * 4;
        int bcol = (bh_ & 15) * 64;
#pragma unroll
        for (int n = 0; n < 4; ++n) {
            int col = bcol + n * 16 + l15;
#pragma unroll
            for (int j = 0; j < 4; ++j)
                Ch[(size_t)(brow + j) * 1024 + col] = (h16)(acc[n][j] + red[tl][n * 4 + j]);
        }
    }
}

// ---------------- V-transpose (single plane) ----------------
__global__ __launch_bounds__(256) void vt_split(
    const h16* __restrict__ inh, int ld, h16* __restrict__ oh)
{
    __shared__ h16 tile[64][68];
    int z = blockIdx.z, b = z >> 4, h = z & 15;
    size_t ibase = ((size_t)b * 512 + blockIdx.x * 64) * ld + h * 64;
    size_t obase = (size_t)z * 32768 + blockIdx.x * 64;
    int tr = threadIdx.x >> 4, tc = (threadIdx.x & 15) * 4;
#pragma unroll
    for (int i = 0; i < 4; ++i) {
        int tt = tr + i * 16;
        short4 v = *(const short4*)(inh + ibase + (size_t)tt * ld + tc);
        tile[tt][tc + 0] = ((h16*)&v)[0];
        tile[tt][tc + 1] = ((h16*)&v)[1];
        tile[tt][tc + 2] = ((h16*)&v)[2];
        tile[tt][tc + 3] = ((h16*)&v)[3];
    }
    __syncthreads();
#pragma unroll
    for (int i = 0; i < 4; ++i) {
        int d = tr + i * 16;
        h16 w[4] = {tile[tc + 0][d], tile[tc + 1][d], tile[tc + 2][d], tile[tc + 3][d]};
        *(short4*)(oh + obase + (size_t)d * 512 + tc) = *(short4*)w;
    }
}

// ---------------- bf16 NT MFMA GEMM (MoE), BK=64, flat grid, XCD pinned, K-split, count-skip ----
template<int TN, bool RELU, bool ROWFAST, int KS>
__global__ __launch_bounds__(256) void gemm_bf16_moe(
    const unsigned short* __restrict__ A,
    const unsigned short* __restrict__ Bt,
    const float* __restrict__ bias,
    unsigned short* __restrict__ C,
    int K, long long sA, long long sB, long long sC, long long sBias, int ldc,
    int emask, int elog, int nrow, int ncol,
    const int* __restrict__ counts, int e0, long long sHalf)
{
    constexpr int NFR = TN / 32;
    __shared__ unsigned short Al[128 * 64];
    __shared__ unsigned short Bl[TN * 64];
    int id = blockIdx.x;
    int e = id & emask;
    int tb = id >> elog;
    int half = 0;
    if (KS == 2) {
        int per = nrow * ncol;
        half = (tb >= per) ? 1 : 0;
        tb -= half * per;
    }
    int row, col;
    if (ROWFAST) { row = tb % nrow; col = tb / nrow; }
    else         { col = tb % ncol; row = tb / ncol; }
    int rowBase = row * 128;

    int bound = counts[e0 + e];
    if (bound > CAPE) bound = CAPE;
    if (rowBase >= bound) return;

    A    += (size_t)e * sA;
    Bt   += (size_t)e * sB;
    bias += (size_t)e * sBias;
    long long zC = (long long)e * sC + (long long)half * sHalf;

    int colBase = col * TN;
    int t = threadIdx.x, lane = t & 63, wid = t >> 6;
    int wr = (wid >> 1) * 64, wc = (wid & 1) * (TN / 2);

    const unsigned short* Ag = A  + (size_t)rowBase * K;
    const unsigned short* Bg = Bt + (size_t)colBase * K;

    f32x4 acc[4][NFR] = {};
    int l15 = lane & 15, g = lane >> 4;

    int kb = half * (K / KS), ke = kb + (K / KS);
    for (int k0 = kb; k0 < ke; k0 += 64) {
        __syncthreads();
#pragma unroll
        for (int cc = 0; cc < 4; ++cc) {
            int c = t + cc * 256;
            int r = c >> 3, sq = (c & 7) ^ (r & 7);
            GLL16(Ag + (size_t)r * K + k0 + sq * 8, &Al[c * 8]);
        }
#pragma unroll
        for (int cc = 0; cc < TN / 32; ++cc) {
            int c = t + cc * 256;
            int r = c >> 3, sq = (c & 7) ^ (r & 7);
            GLL16(Bg + (size_t)r * K + k0 + sq * 8, &Bl[c * 8]);
        }
        __syncthreads();

        bfrag b[2][NFR];
#pragma unroll
        for (int kk = 0; kk < 2; ++kk)
#pragma unroll
            for (int n = 0; n < NFR; ++n) {
                int rr = wc + n * 16 + l15;
                int q = ((kk << 2) | g) ^ (rr & 7);
                b[kk][n] = *(const bfrag*)&Bl[rr * 64 + q * 8];
            }
#pragma unroll
        for (int m = 0; m < 4; ++m) {
            int rr = wr + m * 16 + l15;
#pragma unroll
            for (int kk = 0; kk < 2; ++kk) {
                int q = ((kk << 2) | g) ^ (rr & 7);
                bfrag a = *(const bfrag*)&Al[rr * 64 + q * 8];
#pragma unroll
                for (int n = 0; n < NFR; ++n)
                    acc[m][n] = __builtin_amdgcn_mfma_f32_16x16x32_bf16(a, b[kk][n], acc[m][n], 0, 0, 0);
            }
        }
    }

    int g4 = g * 4;
#pragma unroll
    for (int m = 0; m < 4; ++m) {
        int row0 = rowBase + wr + m * 16 + g4;
#pragma unroll
        for (int n = 0; n < NFR; ++n) {
            int cc = colBase + wc + n * 16 + l15;
            float bv = (KS == 1 || half == 0) ? bias[cc] : 0.f;
#pragma unroll
            for (int j = 0; j < 4; ++j) {
                float v = acc[m][n][j] + bv;
                if (RELU) v = fmaxf(v, 0.f);
                C[zC + (size_t)(row0 + j) * ldc + cc] = f2bf(v);
            }
        }
    }
}

// ---------------- transpose+convert fp32 [R][Cn] -> bf16 [Cn][R] (per z) ----------------
__global__ __launch_bounds__(256) void tcvt_kernel(const float* __restrict__ in,
    unsigned short* __restrict__ out, int R, int Cn)
{
    __shared__ unsigned short tile[64][68];
    size_t zoff = (size_t)blockIdx.z * R * Cn;
    in += zoff; out += zoff;
    int r0 = blockIdx.y * 64, c0 = blockIdx.x * 64;
    int tr = threadIdx.x >> 4, tc = (threadIdx.x & 15) * 4;
#pragma unroll
    for (int i = 0; i < 4; ++i) {
        int r = tr + i * 16;
        float4 v = *(const float4*)&in[(size_t)(r0 + r) * Cn + c0 + tc];
        tile[r][tc + 0] = f2bf(v.x);
        tile[r][tc + 1] = f2bf(v.y);
        tile[r][tc + 2] = f2bf(v.z);
        tile[r][tc + 3] = f2bf(v.w);
    }
    __syncthreads();
#pragma unroll
    for (int i = 0; i < 4; ++i) {
        int c = tr + i * 16;
        ushort4 w;
        w.x = tile[tc + 0][c];
        w.y = tile[tc + 1][c];
        w.z = tile[tc + 2][c];
        w.w = tile[tc + 3][c];
        *(ushort4*)&out[(size_t)(c0 + c) * R + r0 + tc] = w;
    }
}

// ---------------- fused LN3 + router ----------------
__global__ __launch_bounds__(256) void ln_router(
    const float* __restrict__ xin, const float* __restrict__ gw, const float* __restrict__ gb,
    const float* __restrict__ rw, const float* __restrict__ rb,
    const float* __restrict__ tmask, float* __restrict__ tln,
    int* __restrict__ eidx, float* __restrict__ gate, int* __restrict__ valid,
    float* __restrict__ partials)
{
    int wid = threadIdx.x >> 6, lane = threadIdx.x & 63;
    int tok = blockIdx.x * 4 + wid;
    __shared__ float wpart[4][10];

    const float* xrow = xin + (size_t)tok * DMODEL;
    float xv[16];
    float s = 0.f, ss = 0.f;
#pragma unroll
    for (int kk = 0; kk < 16; ++kk) {
        float x = xrow[lane + (kk << 6)];
        xv[kk] = x; s += x; ss += x * x;
    }
#pragma unroll
    for (int o = 1; o < 64; o <<= 1) { s += __shfl_xor(s, o, 64); ss += __shfl_xor(ss, o, 64); }
    float mean = s * (1.0f / DMODEL);
    float var  = ss * (1.0f / DMODEL) - mean * mean;
    float inv  = rsqrtf(var + 1e-5f);

    float acc[8] = {0,0,0,0,0,0,0,0};
#pragma unroll 4
    for (int kk = 0; kk < 16; ++kk) {
        int d = lane + (kk << 6);
        float xd = (xv[kk] - mean) * inv * gw[d] + gb[d];
        tln[(size_t)tok * DMODEL + d] = xd;
        const float4* rp = (const float4*)(rw + (size_t)d * 8);
        float4 r0 = rp[0], r1 = rp[1];
        acc[0] = fmaf(xd, r0.x, acc[0]); acc[1] = fmaf(xd, r0.y, acc[1]);
        acc[2] = fmaf(xd, r0.z, acc[2]); acc[3] = fmaf(xd, r0.w, acc[3]);
        acc[4] = fmaf(xd, r1.x, acc[4]); acc[5] = fmaf(xd, r1.y, acc[5]);
        acc[6] = fmaf(xd, r1.z, acc[6]); acc[7] = fmaf(xd, r1.w, acc[7]);
    }
#pragma unroll
    for (int e = 0; e < 8; ++e)
#pragma unroll
        for (int o = 1; o < 64; o <<= 1) acc[e] += __shfl_xor(acc[e], o, 64);

    if (lane == 0) {
        float l[8]; float m = -1e30f;
#pragma unroll
        for (int e = 0; e < 8; ++e) { l[e] = acc[e] + rb[e]; m = fmaxf(m, l[e]); }
        float se = 0.f;
#pragma unroll
        for (int e = 0; e < 8; ++e) se += expf(l[e] - m);
        int am = 0; float bm = l[0];
#pragma unroll
        for (int e = 1; e < 8; ++e) if (l[e] > bm) { bm = l[e]; am = e; }
        float inv_se = 1.0f / se;
        float g = expf(l[am] - m) * inv_se;
        float vld = (tmask[tok] > 0.f) ? 1.f : 0.f;
        eidx[tok] = am; gate[tok] = g; valid[tok] = (int)vld;
#pragma unroll
        for (int e = 0; e < 8; ++e) wpart[wid][e] = expf(l[e] - m) * inv_se * vld;
        float lse = logf(se) + m;
        wpart[wid][8] = lse * lse * vld;
        wpart[wid][9] = vld;
    }
    __syncthreads();
    if (threadIdx.x == 0) {
        for (int j = 0; j < 10; ++j)
            partials[blockIdx.x * 10 + j] = wpart[0][j] + wpart[1][j] + wpart[2][j] + wpart[3][j];
    }
}

// ---------------- capacity scan ----------------
__global__ __launch_bounds__(256) void scan_kernel(
    const int* __restrict__ eidx, const int* __restrict__ valid, const float* __restrict__ gate,
    int* __restrict__ pc, float* __restrict__ gk, int* __restrict__ keepf,
    int* __restrict__ counts)
{
    __shared__ int cnt[256][8];
    int tid = threadIdx.x;
    int local[8] = {0,0,0,0,0,0,0,0};
    int base = tid * 16;
    for (int i = 0; i < 16; ++i) { int e = eidx[base + i]; local[e] += valid[base + i]; }
#pragma unroll
    for (int e = 0; e < 8; ++e) cnt[tid][e] = local[e];
    __syncthreads();
    if (tid < 8) {
        int run = 0;
        for (int i = 0; i < 256; ++i) { int t = cnt[i][tid]; cnt[i][tid] = run; run += t; }
        counts[tid] = run;
    }
    __syncthreads();
    int off[8];
#pragma unroll
    for (int e = 0; e < 8; ++e) off[e] = cnt[tid][e];
    for (int i = 0; i < 16; ++i) {
        int tok = base + i;
        int e = eidx[tok], v = valid[tok];
        int pos = off[e]; off[e] += v;
        int kp = (v && pos < CAPE) ? 1 : 0;
        pc[tok]    = (pos < CAPE) ? pos : (CAPE - 1);
        keepf[tok] = kp;
        gk[tok]    = kp ? gate[tok] : 0.f;
    }
}

// ---------------- dispatch (expert-range) -> bf16 buffers ----------------
__global__ __launch_bounds__(256) void dispatch_bf16(const float* __restrict__ tln,
    const int* __restrict__ eidx, const int* __restrict__ pc, const int* __restrict__ keepf,
    unsigned short* __restrict__ buf, int e0, int ec)
{
    int tok = blockIdx.x;
    if (!keepf[tok]) return;
    int e = eidx[tok];
    if (e < e0 || e >= e0 + ec) return;
    int p = pc[tok];
    const float4 v = ((const float4*)(tln + (size_t)tok * DMODEL))[threadIdx.x];
    ushort4 o;
    o.x = f2bf(v.x); o.y = f2bf(v.y); o.z = f2bf(v.z); o.w = f2bf(v.w);
    ((ushort4*)(buf + ((size_t)(e - e0) * CAPE + p) * DMODEL))[threadIdx.x] = o;
}

// ---------------- combine add: out += gk * (ob0 + ob1) ----------------
__global__ __launch_bounds__(256) void combine_bf16(const unsigned short* __restrict__ ob,
    const int* __restrict__ eidx, const int* __restrict__ pc, const float* __restrict__ gk,
    float* __restrict__ out, int e0, int ec, long long sHalf)
{
    int tok = blockIdx.x;
    int e = eidx[tok];
    if (e < e0 || e >= e0 + ec) return;
    float g = gk[tok];
    int p = pc[tok];
    size_t idx = ((size_t)(e - e0) * CAPE + p) * DMODEL;
    float4* o = (float4*)(out + (size_t)tok * DMODEL);
    const ushort4 u0 = ((const ushort4*)(ob + idx))[threadIdx.x];
    const ushort4 u1 = ((const ushort4*)(ob + sHalf + idx))[threadIdx.x];
    float4 a = o[threadIdx.x];
    a.x += g * (bf2f(u0.x) + bf2f(u1.x));
    a.y += g * (bf2f(u0.y) + bf2f(u1.y));
    a.z += g * (bf2f(u0.z) + bf2f(u1.z));
    a.w += g * (bf2f(u0.w) + bf2f(u1.w));
    o[threadIdx.x] = a;
}

// ---------------- final scalar losses (1024 partials, 16/lane) ----------------
__global__ __launch_bounds__(64) void loss_kernel(const float* __restrict__ partials,
    const int* __restrict__ counts, float* __restrict__ out2)
{
    int lane = threadIdx.x;
    float p[10] = {0,0,0,0,0,0,0,0,0,0};
    for (int r = 0; r < 16; ++r) {
        const float* row = partials + ((size_t)lane * 16 + r) * 10;
#pragma unroll
        for (int j = 0; j < 10; ++j) p[j] += row[j];
    }
#pragma unroll
    for (int j = 0; j < 10; ++j)
#pragma unroll
        for (int o = 1; o < 64; o <<= 1) p[j] += __shfl_xor(p[j], o, 64);
    if (lane == 0) {
        float nv = fmaxf(p[9], 1.f);
        float lb = 0.f;
        for (int e = 0; e < 8; ++e) lb += ((float)counts[e] / nv) * (p[e] / nv);
        lb *= (float)NEXP;
        out2[0] = lb;
        out2[1] = p[8] / nv;
    }
}

// ---------------- host launch ----------------
extern "C" void kernel_launch(void* const* d_in, const int* in_sizes, int n_in,
                              void* d_out, int out_size, void* d_ws, size_t ws_size,
                              hipStream_t stream)
{
    const float* tgt        = (const float*)d_in[0];
    const float* src        = (const float*)d_in[1];
    const float* token_mask = (const float*)d_in[5];
    const float* ln1w = (const float*)d_in[6],  *ln1b = (const float*)d_in[7];
    const float* self_in_w  = (const float*)d_in[8],  *self_in_b  = (const float*)d_in[9];
    const float* self_out_w = (const float*)d_in[10], *self_out_b = (const float*)d_in[11];
    const float* ln2w = (const float*)d_in[12], *ln2b = (const float*)d_in[13];
    const float* enc_in_w   = (const float*)d_in[14], *enc_in_b   = (const float*)d_in[15];
    const float* enc_out_w  = (const float*)d_in[16], *enc_out_b  = (const float*)d_in[17];
    const float* ln3w = (const float*)d_in[18], *ln3b = (const float*)d_in[19];
    const float* rw = (const float*)d_in[20], *rb = (const float*)d_in[21];
    const float* w1 = (const float*)d_in[22], *b1 = (const float*)d_in[23];
    const float* w2 = (const float*)d_in[24], *b2 = (const float*)d_in[25];

    float* out = (float*)d_out;          // residual stream lives HERE
    float* ws  = (float*)d_ws;

    // ---- fixed layout (floats) ----
    float* tln = ws;                         // 4,194,304
    float* ctx = ws + 4194304;               // ctx single-plane f16 (2,097,152 floats used)
    int*   eidxA   = (int*)(ws + 8388608);
    int*   validA  = eidxA + 4096;
    int*   pcA     = validA + 4096;
    int*   keepA   = pcA + 4096;
    int*   countsA = keepA + 4096;           // 16
    float* gateA   = (float*)(countsA + 16);
    float* gkA     = gateA + 4096;
    float* partA   = gkA + 4096;             // 1024*10
    const size_t POOL_OFF = 8425984;         // floats
    float* pool = ws + POOL_OFF;

    size_t Wf = ws_size / sizeof(float);
    size_t pf = (Wf > POOL_OFF) ? (Wf - POOL_OFF) : 0;

    // tiers: bg batches/group, zc score z-chunk
    int bg, zc;
    if      (pf >= 31457280) { bg = 8; zc = 128; }
    else if (pf >= 23068672) { bg = 8; zc = 32; }
    else if (pf >= 12582912) { bg = 4; zc = 16; }
    else                     { bg = 2; zc = 16; }
    int ecs = 1;
    for (int c = 8; c >= 1; c >>= 1)
        if ((size_t)c * 4063232ull <= pf) { ecs = c; break; }
    int elog = (ecs == 8) ? 3 : (ecs == 4) ? 2 : (ecs == 2) ? 1 : 0;

    float* qreg = pool;
    float* vreg = qreg + (size_t)bg * 1572864;
    float* sreg = vreg + (size_t)bg * 262144;

    h16* tlnh = (h16*)tln;
    h16* tlnl = tlnh + 4194304;
    h16* ctxh = (h16*)ctx;

    // ================= self attention =================
    ln_hl<<<NTOK, 256, 0, stream>>>(tgt, ln1w, ln1b, tlnh, tlnl);

    for (int g0 = 0; g0 < BATCH; g0 += bg) {
        h16* sb  = (h16*)sreg;
        h16* whi = sb, *wlo = sb + 3145728;
        split_f16<<<1536, 256, 0, stream>>>(self_in_w, whi, wlo, 393216);

        h16* qkvh = (h16*)qreg, *qkvl = qkvh + (size_t)bg * 1572864;
        gemm_f16x2_nt<2, 2><<<dim3(24, bg * 4, 1), 256, 0, stream>>>(
            tlnh + (size_t)g0 * 524288, tlnl + (size_t)g0 * 524288, 1024,
            whi, wlo, 1024, self_in_b, nullptr,
            nullptr, qkvh, qkvl, 1024, 3072);

        h16* vth = (h16*)vreg;
        vt_split<<<dim3(8, 1, bg * 16), 256, 0, stream>>>(qkvh + 2048, 3072, vth);

        h16* sh = sb;
        for (int c0 = 0; c0 < bg * 16; c0 += zc) {
            attn_qk<true><<<dim3(4, 4, zc), 256, 0, stream>>>(
                qkvh, qkvl, 3072, qkvh + 1024, qkvl + 1024, 3072, sh, c0);
            attn_pv<true><<<dim3(8, 1, zc), 512, 0, stream>>>(
                sh, vth + (size_t)c0 * 32768, ctxh, g0 * 16 + c0);
        }
    }
    {
        h16* sb = (h16*)sreg;
        h16* owhi = sb, *owlo = sb + 1048576;
        split_f16<<<512, 256, 0, stream>>>(self_out_w, owhi, owlo, 131072);
        gemm_f16x2_nt<1, 1><<<dim3(8, 32, 1), 256, 0, stream>>>(
            ctxh, nullptr, 1024, owhi, owlo, 1024, self_out_b, tgt,
            out, nullptr, nullptr, 1024, 1024);
    }

    // ================= cross attention =================
    ln_hl<<<NTOK, 256, 0, stream>>>(out, ln2w, ln2b, tlnh, tlnl);

    for (int g0 = 0; g0 < BATCH; g0 += bg) {
        h16* sb  = (h16*)sreg;
        h16* shi = sb, *slo = sb + (size_t)bg * 524288;
        h16* ehi = sb + (size_t)bg * 1048576, *elo = ehi + 3145728;
        split_f16<<<bg * 256, 256, 0, stream>>>(src + (size_t)g0 * 524288, shi, slo, bg * 65536);
        split_f16<<<1536, 256, 0, stream>>>(enc_in_w, ehi, elo, 393216);

        h16* q2h  = (h16*)qreg,                 *q2l  = q2h + (size_t)bg * 524288;
        h16* kv2h = q2h + (size_t)bg * 1048576, *kv2l = kv2h + (size_t)bg * 1048576;
        gemm_f16x2_nt<2, 2><<<dim3(8, bg * 4, 1), 256, 0, stream>>>(
            tlnh + (size_t)g0 * 524288, tlnl + (size_t)g0 * 524288, 1024,
            ehi, elo, 1024, enc_in_b, nullptr,
            nullptr, q2h, q2l, 1024, 1024);
        gemm_f16x2_nt<2, 2><<<dim3(16, bg * 4, 1), 256, 0, stream>>>(
            shi, slo, 1024, ehi + 1048576, elo + 1048576, 1024, enc_in_b + 1024, nullptr,
            nullptr, kv2h, kv2l, 1024, 2048);

        h16* vth = (h16*)vreg;
        vt_split<<<dim3(8, 1, bg * 16), 256, 0, stream>>>(kv2h + 1024, 2048, vth);

        h16* sh = sb;
        for (int c0 = 0; c0 < bg * 16; c0 += zc) {
            attn_qk<false><<<dim3(4, 4, zc), 256, 0, stream>>>(
                q2h, q2l, 1024, kv2h, kv2l, 2048, sh, c0);
            attn_pv<false><<<dim3(8, 1, zc), 512, 0, stream>>>(
                sh, vth + (size_t)c0 * 32768, ctxh, g0 * 16 + c0);
        }
    }
    {
        h16* sb = (h16*)sreg;
        h16* owhi = sb, *owlo = sb + 1048576;
        split_f16<<<512, 256, 0, stream>>>(enc_out_w, owhi, owlo, 131072);
        gemm_f16x2_nt<1, 1><<<dim3(8, 32, 1), 256, 0, stream>>>(
            ctxh, nullptr, 1024, owhi, owlo, 1024, enc_out_b, out,
            out, nullptr, nullptr, 1024, 1024);
    }

    // ================= MoE =================
    ln_router<<<1024, 256, 0, stream>>>(out, ln3w, ln3b, rw, rb, token_mask, tln,
                                        eidxA, gateA, validA, partA);
    scan_kernel<<<1, 256, 0, stream>>>(eidxA, validA, gateA, pcA, gkA, keepA, countsA);

    long long sHalf = 0;
    for (int e0 = 0; e0 < NEXP; e0 += ecs) {
        unsigned short* wt   = (unsigned short*)pool;
        unsigned short* hB   = (unsigned short*)(pool + (size_t)ecs * 2097152);
        unsigned short* bufB = (unsigned short*)(pool + (size_t)ecs * 3407872);
        unsigned short* obB  = bufB;                       // ob0 overlays bufB
        sHalf = (long long)ecs * 655360;

        tcvt_kernel<<<dim3(64, 16, ecs), 256, 0, stream>>>(
            w1 + (size_t)e0 * 4194304, wt, 1024, 4096);
        dispatch_bf16<<<NTOK, 256, 0, stream>>>(tln, eidxA, pcA, keepA, bufB, e0, ecs);
        gemm_bf16_moe<128, true, true, 1><<<ecs * 5 * 32, 256, 0, stream>>>(
            bufB, wt, b1 + (size_t)e0 * 4096, hB,
            1024, 655360LL, 4194304LL, 2621440LL, 4096LL, 4096,
            ecs - 1, elog, 5, 32, countsA, e0, 0LL);

        tcvt_kernel<<<dim3(16, 64, ecs), 256, 0, stream>>>(
            w2 + (size_t)e0 * 4194304, wt, 4096, 1024);
        gemm_bf16_moe<64, false, false, 2><<<ecs * 5 * 16 * 2, 256, 0, stream>>>(
            hB, wt, b2 + (size_t)e0 * 1024, obB,
            4096, 2621440LL, 4194304LL, 655360LL, 1024LL, 1024,
            ecs - 1, elog, 5, 16, countsA, e0, sHalf);

        combine_bf16<<<NTOK, 256, 0, stream>>>(obB, eidxA, pcA, gkA, out, e0, ecs, sHalf);
    }

    // ===== losses =====
    loss_kernel<<<1, 64, 0, stream>>>(partA, countsA, out + (size_t)NTOK * DMODEL);
}

// Round 16
// 542.695 us; speedup vs baseline: 4.9881x; 1.2150x over previous
//
#include <hip/hip_runtime.h>
#include <cstdint>

// ---------------- problem constants ----------------
constexpr int BATCH  = 8;
constexpr int TSEQ   = 512;
constexpr int DMODEL = 1024;
constexpr int NEXP   = 8;
constexpr int CAPE   = 640;
constexpr int NTOK   = BATCH * TSEQ;        // 4096

typedef _Float16 h16;
typedef __attribute__((ext_vector_type(8))) short bfrag;
typedef __attribute__((ext_vector_type(8))) _Float16 hfrag;
typedef __attribute__((ext_vector_type(4))) float f32x4;

__device__ __forceinline__ unsigned short f2bf(float f) {
    uint32_t u = __float_as_uint(f);
    uint32_t r = (u + 0x7FFFu + ((u >> 16) & 1u)) >> 16;   // RNE
    return (unsigned short)r;
}
__device__ __forceinline__ float bf2f(unsigned short b) {
    return __uint_as_float((uint32_t)b << 16);
}

#define GLL16(SRC, DST) __builtin_amdgcn_global_load_lds( \
    (const __attribute__((address_space(1))) void*)(SRC), \
    (__attribute__((address_space(3))) void*)(DST), 16, 0, 0)

// ---------------- LayerNorm -> single f16 ----------------
__global__ __launch_bounds__(256) void ln_f16(const float* __restrict__ in,
    const float* __restrict__ gw, const float* __restrict__ gb,
    h16* __restrict__ oh)
{
    int row = blockIdx.x, tid = threadIdx.x;
    const float4 v = *(const float4*)(in + (size_t)row * DMODEL + tid * 4);
    float s  = v.x + v.y + v.z + v.w;
    float ss = v.x*v.x + v.y*v.y + v.z*v.z + v.w*v.w;
#pragma unroll
    for (int o = 1; o < 64; o <<= 1) { s += __shfl_xor(s, o, 64); ss += __shfl_xor(ss, o, 64); }
    __shared__ float rs[4], rss[4];
    int wid = tid >> 6, lane = tid & 63;
    if (lane == 0) { rs[wid] = s; rss[wid] = ss; }
    __syncthreads();
    s  = rs[0] + rs[1] + rs[2] + rs[3];
    ss = rss[0] + rss[1] + rss[2] + rss[3];
    float mean = s * (1.0f / DMODEL);
    float var  = ss * (1.0f / DMODEL) - mean * mean;
    float inv  = rsqrtf(var + 1e-5f);
    float4 w4 = *(const float4*)(gw + tid * 4);
    float4 b4 = *(const float4*)(gb + tid * 4);
    short4 hv;
    ((h16*)&hv)[0] = (h16)((v.x - mean) * inv * w4.x + b4.x);
    ((h16*)&hv)[1] = (h16)((v.y - mean) * inv * w4.y + b4.y);
    ((h16*)&hv)[2] = (h16)((v.z - mean) * inv * w4.z + b4.z);
    ((h16*)&hv)[3] = (h16)((v.w - mean) * inv * w4.w + b4.w);
    *(short4*)(oh + (size_t)row * DMODEL + tid * 4) = hv;
}

// ---------------- fp32 -> f16 single convert ----------------
__global__ __launch_bounds__(256) void cvt_f16(const float* __restrict__ in,
    h16* __restrict__ out, int n8)
{
    int i = blockIdx.x * 256 + threadIdx.x;
    if (i >= n8) return;
    const float4* p = (const float4*)in + 2 * (size_t)i;
    float4 v0 = p[0], v1 = p[1];
    float vv[8] = {v0.x, v0.y, v0.z, v0.w, v1.x, v1.y, v1.z, v1.w};
    hfrag h;
#pragma unroll
    for (int j = 0; j < 8; ++j) h[j] = (h16)vv[j];
    ((hfrag*)out)[i] = h;
}

// ---------------- fp32 -> fp16 hi/lo split (out-proj weights) ----------------
__global__ __launch_bounds__(256) void split_f16(const float* __restrict__ in,
    h16* __restrict__ hi, h16* __restrict__ lo, int n8)
{
    int i = blockIdx.x * 256 + threadIdx.x;
    if (i >= n8) return;
    const float4* p = (const float4*)in + 2 * (size_t)i;
    float4 v0 = p[0], v1 = p[1];
    float vv[8] = {v0.x, v0.y, v0.z, v0.w, v1.x, v1.y, v1.z, v1.w};
    hfrag h, l;
#pragma unroll
    for (int j = 0; j < 8; ++j) {
        h16 hj = (h16)vv[j];
        h[j] = hj;
        l[j] = (h16)(vv[j] - (float)hj);
    }
    ((hfrag*)hi)[i] = h;
    ((hfrag*)lo)[i] = l;
}

// ---------------- pure-f16 1-product NT GEMM, BK=128, f16 out + bias ----------------
__global__ __launch_bounds__(256) void gemm_f16(
    const h16* __restrict__ A, int lda,
    const h16* __restrict__ B, int ldb,
    const float* __restrict__ bias,
    h16* __restrict__ Cf, int K, int ldc)
{
    __shared__ h16 AL[16384], BL[16384];   // 128x128 f16 each, 64 KB
    int rowBase = blockIdx.y * 128, colBase = blockIdx.x * 128;
    int t = threadIdx.x, lane = t & 63, wid = t >> 6;
    int wr = (wid >> 1) * 64, wc = (wid & 1) * 64;
    const h16* Ag = A + (size_t)rowBase * lda;
    const h16* Bg = B + (size_t)colBase * ldb;
    f32x4 acc[4][4] = {};
    int l15 = lane & 15, g = lane >> 4;

    for (int k0 = 0; k0 < K; k0 += 128) {
        __syncthreads();
#pragma unroll
        for (int cc = 0; cc < 8; ++cc) {
            int c = t + cc * 256;
            int r = c >> 4, sq = (c & 15) ^ (r & 15);
            GLL16(Ag + (size_t)r * lda + k0 + sq * 8, &AL[c * 8]);
            GLL16(Bg + (size_t)r * ldb + k0 + sq * 8, &BL[c * 8]);
        }
        __syncthreads();

#pragma unroll
        for (int kk = 0; kk < 4; ++kk) {
            hfrag bv[4];
#pragma unroll
            for (int n = 0; n < 4; ++n) {
                int rr = wc + n * 16 + l15;
                int q = ((kk << 2) | g) ^ (rr & 15);
                bv[n] = *(const hfrag*)&BL[rr * 128 + q * 8];
            }
#pragma unroll
            for (int m = 0; m < 4; ++m) {
                int rr = wr + m * 16 + l15;
                int q = ((kk << 2) | g) ^ (rr & 15);
                hfrag a = *(const hfrag*)&AL[rr * 128 + q * 8];
#pragma unroll
                for (int n = 0; n < 4; ++n)
                    acc[m][n] = __builtin_amdgcn_mfma_f32_16x16x32_f16(a, bv[n], acc[m][n], 0, 0, 0);
            }
        }
    }

    int g4 = g * 4;
#pragma unroll
    for (int m = 0; m < 4; ++m) {
        int row0 = rowBase + wr + m * 16 + g4;
#pragma unroll
        for (int n = 0; n < 4; ++n) {
            int col = colBase + wc + n * 16 + l15;
            float bv = bias[col];
#pragma unroll
            for (int j = 0; j < 4; ++j)
                Cf[(size_t)(row0 + j) * ldc + col] = (h16)(acc[m][n][j] + bv);
        }
    }
}

// ---------------- fp16 split NT MFMA GEMM (out-proj), BK=64, A single, B hi/lo ----------------
__global__ __launch_bounds__(256) void gemm_f16x2_nt(
    const h16* __restrict__ Ahi, int lda,
    const h16* __restrict__ Bhi, const h16* __restrict__ Blo, int ldb,
    const float* __restrict__ bias, const float* __restrict__ res,
    float* __restrict__ C, int K, int ldc)
{
    __shared__ h16 AhL[8192], BhL[8192], BlL[8192];
    int rowBase = blockIdx.y * 128, colBase = blockIdx.x * 128;
    int t = threadIdx.x, lane = t & 63, wid = t >> 6;
    int wr = (wid >> 1) * 64, wc = (wid & 1) * 64;
    const h16* Ah = Ahi + (size_t)rowBase * lda;
    const h16* Bh = Bhi + (size_t)colBase * ldb;
    const h16* Bl = Blo + (size_t)colBase * ldb;
    f32x4 acc[4][4] = {};
    int l15 = lane & 15, g = lane >> 4;

    for (int k0 = 0; k0 < K; k0 += 64) {
        __syncthreads();
#pragma unroll
        for (int cc = 0; cc < 4; ++cc) {
            int c = t + cc * 256;
            int r = c >> 3, sq = (c & 7) ^ (r & 7);
            GLL16(Ah + (size_t)r * lda + k0 + sq * 8, &AhL[c * 8]);
            GLL16(Bh + (size_t)r * ldb + k0 + sq * 8, &BhL[c * 8]);
            GLL16(Bl + (size_t)r * ldb + k0 + sq * 8, &BlL[c * 8]);
        }
        __syncthreads();

#pragma unroll
        for (int kk = 0; kk < 2; ++kk) {
            hfrag bh[4], bl[4];
#pragma unroll
            for (int n = 0; n < 4; ++n) {
                int rr = wc + n * 16 + l15;
                int q = ((kk << 2) | g) ^ (rr & 7);
                bh[n] = *(const hfrag*)&BhL[rr * 64 + q * 8];
                bl[n] = *(const hfrag*)&BlL[rr * 64 + q * 8];
            }
#pragma unroll
            for (int m = 0; m < 4; ++m) {
                int rr = wr + m * 16 + l15;
                int q = ((kk << 2) | g) ^ (rr & 7);
                hfrag ah = *(const hfrag*)&AhL[rr * 64 + q * 8];
#pragma unroll
                for (int n = 0; n < 4; ++n) {
                    acc[m][n] = __builtin_amdgcn_mfma_f32_16x16x32_f16(ah, bh[n], acc[m][n], 0, 0, 0);
                    acc[m][n] = __builtin_amdgcn_mfma_f32_16x16x32_f16(ah, bl[n], acc[m][n], 0, 0, 0);
                }
            }
        }
    }

    int g4 = g * 4;
#pragma unroll
    for (int m = 0; m < 4; ++m) {
        int row0 = rowBase + wr + m * 16 + g4;
#pragma unroll
        for (int n = 0; n < 4; ++n) {
            int col = colBase + wc + n * 16 + l15;
            float bv = bias[col];
#pragma unroll
            for (int j = 0; j < 4; ++j) {
                float v = acc[m][n][j] + bv + res[(size_t)(row0 + j) * ldc + col];
                C[(size_t)(row0 + j) * ldc + col] = v;
            }
        }
    }
}

// ---------------- attention QK^T (pure f16 1-product, K=64 single step) ----------------
template<bool CAUSAL>
__global__ __launch_bounds__(256) void attn_qk(
    const h16* __restrict__ Q, int lda,
    const h16* __restrict__ Km, int ldb,
    h16* __restrict__ Sh, int zoff)
{
    int rowBase = blockIdx.y * 128, colBase = blockIdx.x * 128;
    if (CAUSAL && colBase >= rowBase + 128) return;
    __shared__ h16 AL[8192], BL[8192];
    int z = blockIdx.z;
    int bh_ = zoff + z, b = bh_ >> 4, h = bh_ & 15;
    const h16* Ag = Q  + (size_t)(b * 512 + rowBase) * lda + h * 64;
    const h16* Bg = Km + (size_t)(b * 512 + colBase) * ldb + h * 64;
    int t = threadIdx.x, lane = t & 63, wid = t >> 6;
    int wr = (wid >> 1) * 64, wc = (wid & 1) * 64;
    f32x4 acc[4][4] = {};
    int l15 = lane & 15, g = lane >> 4;

#pragma unroll
    for (int cc = 0; cc < 4; ++cc) {
        int c = t + cc * 256;
        int r = c >> 3, sq = (c & 7) ^ (r & 7);
        GLL16(Ag + (size_t)r * lda + sq * 8, &AL[c * 8]);
        GLL16(Bg + (size_t)r * ldb + sq * 8, &BL[c * 8]);
    }
    __syncthreads();

#pragma unroll
    for (int kk = 0; kk < 2; ++kk) {
        hfrag bv[4];
#pragma unroll
        for (int n = 0; n < 4; ++n) {
            int rr = wc + n * 16 + l15;
            int q = ((kk << 2) | g) ^ (rr & 7);
            bv[n] = *(const hfrag*)&BL[rr * 64 + q * 8];
        }
#pragma unroll
        for (int m = 0; m < 4; ++m) {
            int rr = wr + m * 16 + l15;
            int q = ((kk << 2) | g) ^ (rr & 7);
            hfrag a = *(const hfrag*)&AL[rr * 64 + q * 8];
#pragma unroll
            for (int n = 0; n < 4; ++n)
                acc[m][n] = __builtin_amdgcn_mfma_f32_16x16x32_f16(a, bv[n], acc[m][n], 0, 0, 0);
        }
    }

    size_t sbase = (size_t)z * 262144;
    int g4 = g * 4;
#pragma unroll
    for (int m = 0; m < 4; ++m) {
        int row0 = rowBase + wr + m * 16 + g4;
#pragma unroll
        for (int n = 0; n < 4; ++n) {
            int col = colBase + wc + n * 16 + l15;
#pragma unroll
            for (int j = 0; j < 4; ++j)
                Sh[sbase + (size_t)(row0 + j) * 512 + col] = (h16)(acc[m][n][j] * 0.125f);
        }
    }
}

// ---------------- fused softmax+PV: 512 threads, in-block K-split, P single f16 ----------------
template<bool CAUSAL>
__global__ __launch_bounds__(512) void attn_pv(
    const h16* __restrict__ Shg,
    const h16* __restrict__ Vh,
    h16* __restrict__ Ch, int bh0)
{
    __shared__ h16 ShL[2][4096], VhL[2][4096];
    __shared__ float red[256][16];
    __shared__ float mS[64], iS[64];
    int z = blockIdx.z, bh_ = bh0 + z;
    int rowBase = blockIdx.x * 64;
    const h16* Sa = Shg + (size_t)z * 262144 + (size_t)rowBase * 512;
    const h16* Va = Vh + (size_t)z * 32768;
    int t = threadIdx.x;
    int wv = t >> 6, lane = t & 63;
    int g2 = wv >> 2, wid = wv & 3, tl = t & 255;
    int l15 = lane & 15, g = lane >> 4;

    {
        int tr = t >> 3, tq = t & 7;
        int limit = CAUSAL ? (rowBase + tr + 1) : 512;
        float m = -1e30f, l = 0.f;
        const h16* rh = Sa + (size_t)tr * 512;
        for (int c = 0; c < 8; ++c) {
            int col0 = tq * 8 + c * 64;
            if (col0 >= limit) break;
            hfrag hv = *(const hfrag*)(rh + col0);
            float s[8]; float cm = -1e30f;
#pragma unroll
            for (int j = 0; j < 8; ++j) {
                float sv = (float)hv[j];
                s[j] = (col0 + j < limit) ? sv : -1e30f;
                cm = fmaxf(cm, s[j]);
            }
            if (cm > m) { l *= __expf(m - cm); m = cm; }
#pragma unroll
            for (int j = 0; j < 8; ++j) l += __expf(s[j] - m);
        }
#pragma unroll
        for (int o = 1; o < 8; o <<= 1) {
            float mo = __shfl_xor(m, o, 64);
            float lo2 = __shfl_xor(l, o, 64);
            float mc = fmaxf(m, mo);
            l = l * __expf(m - mc) + lo2 * __expf(mo - mc);
            m = mc;
        }
        if (tq == 0) { mS[tr] = m; iS[tr] = 1.0f / l; }
    }
    __syncthreads();

    int arow = wid * 16 + l15;
    float am = mS[arow], ai = iS[arow];
    int alim = CAUSAL ? (rowBase + arow + 1) : 512;
    int kend = CAUSAL ? (rowBase + 64) : 512;
    int nck = kend >> 6;
    f32x4 acc[4] = {};

    for (int ci = 0; ci < nck; ci += 2) {
        int myck = ci + g2;
        bool act = myck < nck;
        int k0 = myck << 6;
        __syncthreads();
        if (act) {
#pragma unroll
            for (int cc = 0; cc < 2; ++cc) {
                int c = tl + cc * 256;
                int r = c >> 3, sq = (c & 7) ^ (r & 7);
                GLL16(Sa + (size_t)r * 512 + k0 + sq * 8, &ShL[g2][c * 8]);
                GLL16(Va + (size_t)r * 512 + k0 + sq * 8, &VhL[g2][c * 8]);
            }
        }
        __syncthreads();
        if (act) {
#pragma unroll
            for (int kk = 0; kk < 2; ++kk) {
                int chunk = (kk << 2) | g;
                int aq = chunk ^ (arow & 7);
                hfrag sh_ = *(const hfrag*)&ShL[g2][arow * 64 + aq * 8];
                int cbase = k0 + chunk * 8;
                hfrag ph;
#pragma unroll
                for (int j = 0; j < 8; ++j) {
                    float p = __expf((float)sh_[j] - am) * ai;
                    ph[j] = (h16)((cbase + j < alim) ? p : 0.f);
                }
#pragma unroll
                for (int n = 0; n < 4; ++n) {
                    int brow = n * 16 + l15;
                    int bq = chunk ^ (brow & 7);
                    hfrag bh = *(const hfrag*)&VhL[g2][brow * 64 + bq * 8];
                    acc[n] = __builtin_amdgcn_mfma_f32_16x16x32_f16(ph, bh, acc[n], 0, 0, 0);
                }
            }
        }
    }

    __syncthreads();
    if (g2 == 1) {
#pragma unroll
        for (int n = 0; n < 4; ++n)
#pragma unroll
            for (int j = 0; j < 4; ++j) red[tl][n * 4 + j] = acc[n][j];
    }
    __syncthreads();
    if (g2 == 0) {
        int brow = (bh_ >> 4) * 512 + rowBase + wid * 16 + g * 4;
        int bcol = (bh_ & 15) * 64;
#pragma unroll
        for (int n = 0; n < 4; ++n) {
            int col = bcol + n * 16 + l15;
#pragma unroll
            for (int j = 0; j < 4; ++j)
                Ch[(size_t)(brow + j) * 1024 + col] = (h16)(acc[n][j] + red[tl][n * 4 + j]);
        }
    }
}

// ---------------- V-transpose (single plane) ----------------
__global__ __launch_bounds__(256) void vt_split(
    const h16* __restrict__ inh, int ld, h16* __restrict__ oh)
{
    __shared__ h16 tile[64][68];
    int z = blockIdx.z, b = z >> 4, h = z & 15;
    size_t ibase = ((size_t)b * 512 + blockIdx.x * 64) * ld + h * 64;
    size_t obase = (size_t)z * 32768 + blockIdx.x * 64;
    int tr = threadIdx.x >> 4, tc = (threadIdx.x & 15) * 4;
#pragma unroll
    for (int i = 0; i < 4; ++i) {
        int tt = tr + i * 16;
        short4 v = *(const short4*)(inh + ibase + (size_t)tt * ld + tc);
        tile[tt][tc + 0] = ((h16*)&v)[0];
        tile[tt][tc + 1] = ((h16*)&v)[1];
        tile[tt][tc + 2] = ((h16*)&v)[2];
        tile[tt][tc + 3] = ((h16*)&v)[3];
    }
    __syncthreads();
#pragma unroll
    for (int i = 0; i < 4; ++i) {
        int d = tr + i * 16;
        h16 w[4] = {tile[tc + 0][d], tile[tc + 1][d], tile[tc + 2][d], tile[tc + 3][d]};
        *(short4*)(oh + obase + (size_t)d * 512 + tc) = *(short4*)w;
    }
}

// ---------------- bf16 NT MFMA GEMM (MoE), BK=64, flat grid, XCD pinned, K-split, count-skip ----
template<int TN, bool RELU, bool ROWFAST, int KS>
__global__ __launch_bounds__(256) void gemm_bf16_moe(
    const unsigned short* __restrict__ A,
    const unsigned short* __restrict__ Bt,
    const float* __restrict__ bias,
    unsigned short* __restrict__ C,
    int K, long long sA, long long sB, long long sC, long long sBias, int ldc,
    int emask, int elog, int nrow, int ncol,
    const int* __restrict__ counts, int e0, long long sHalf)
{
    constexpr int NFR = TN / 32;
    __shared__ unsigned short Al[128 * 64];
    __shared__ unsigned short Bl[TN * 64];
    int id = blockIdx.x;
    int e = id & emask;
    int tb = id >> elog;
    int half = 0;
    if (KS == 2) {
        int per = nrow * ncol;
        half = (tb >= per) ? 1 : 0;
        tb -= half * per;
    }
    int row, col;
    if (ROWFAST) { row = tb % nrow; col = tb / nrow; }
    else         { col = tb % ncol; row = tb / ncol; }
    int rowBase = row * 128;

    int bound = counts[e0 + e];
    if (bound > CAPE) bound = CAPE;
    if (rowBase >= bound) return;

    A    += (size_t)e * sA;
    Bt   += (size_t)e * sB;
    bias += (size_t)e * sBias;
    long long zC = (long long)e * sC + (long long)half * sHalf;

    int colBase = col * TN;
    int t = threadIdx.x, lane = t & 63, wid = t >> 6;
    int wr = (wid >> 1) * 64, wc = (wid & 1) * (TN / 2);

    const unsigned short* Ag = A  + (size_t)rowBase * K;
    const unsigned short* Bg = Bt + (size_t)colBase * K;

    f32x4 acc[4][NFR] = {};
    int l15 = lane & 15, g = lane >> 4;

    int kb = half * (K / KS), ke = kb + (K / KS);
    for (int k0 = kb; k0 < ke; k0 += 64) {
        __syncthreads();
#pragma unroll
        for (int cc = 0; cc < 4; ++cc) {
            int c = t + cc * 256;
            int r = c >> 3, sq = (c & 7) ^ (r & 7);
            GLL16(Ag + (size_t)r * K + k0 + sq * 8, &Al[c * 8]);
        }
#pragma unroll
        for (int cc = 0; cc < TN / 32; ++cc) {
            int c = t + cc * 256;
            int r = c >> 3, sq = (c & 7) ^ (r & 7);
            GLL16(Bg + (size_t)r * K + k0 + sq * 8, &Bl[c * 8]);
        }
        __syncthreads();

        bfrag b[2][NFR];
#pragma unroll
        for (int kk = 0; kk < 2; ++kk)
#pragma unroll
            for (int n = 0; n < NFR; ++n) {
                int rr = wc + n * 16 + l15;
                int q = ((kk << 2) | g) ^ (rr & 7);
                b[kk][n] = *(const bfrag*)&Bl[rr * 64 + q * 8];
            }
#pragma unroll
        for (int m = 0; m < 4; ++m) {
            int rr = wr + m * 16 + l15;
#pragma unroll
            for (int kk = 0; kk < 2; ++kk) {
                int q = ((kk << 2) | g) ^ (rr & 7);
                bfrag a = *(const bfrag*)&Al[rr * 64 + q * 8];
#pragma unroll
                for (int n = 0; n < NFR; ++n)
                    acc[m][n] = __builtin_amdgcn_mfma_f32_16x16x32_bf16(a, b[kk][n], acc[m][n], 0, 0, 0);
            }
        }
    }

    int g4 = g * 4;
#pragma unroll
    for (int m = 0; m < 4; ++m) {
        int row0 = rowBase + wr + m * 16 + g4;
#pragma unroll
        for (int n = 0; n < NFR; ++n) {
            int cc = colBase + wc + n * 16 + l15;
            float bv = (KS == 1 || half == 0) ? bias[cc] : 0.f;
#pragma unroll
            for (int j = 0; j < 4; ++j) {
                float v = acc[m][n][j] + bv;
                if (RELU) v = fmaxf(v, 0.f);
                C[zC + (size_t)(row0 + j) * ldc + cc] = f2bf(v);
            }
        }
    }
}

// ---------------- transpose+convert fp32 [R][Cn] -> bf16 [Cn][R] (per z) ----------------
__global__ __launch_bounds__(256) void tcvt_kernel(const float* __restrict__ in,
    unsigned short* __restrict__ out, int R, int Cn)
{
    __shared__ unsigned short tile[64][68];
    size_t zoff = (size_t)blockIdx.z * R * Cn;
    in += zoff; out += zoff;
    int r0 = blockIdx.y * 64, c0 = blockIdx.x * 64;
    int tr = threadIdx.x >> 4, tc = (threadIdx.x & 15) * 4;
#pragma unroll
    for (int i = 0; i < 4; ++i) {
        int r = tr + i * 16;
        float4 v = *(const float4*)&in[(size_t)(r0 + r) * Cn + c0 + tc];
        tile[r][tc + 0] = f2bf(v.x);
        tile[r][tc + 1] = f2bf(v.y);
        tile[r][tc + 2] = f2bf(v.z);
        tile[r][tc + 3] = f2bf(v.w);
    }
    __syncthreads();
#pragma unroll
    for (int i = 0; i < 4; ++i) {
        int c = tr + i * 16;
        ushort4 w;
        w.x = tile[tc + 0][c];
        w.y = tile[tc + 1][c];
        w.z = tile[tc + 2][c];
        w.w = tile[tc + 3][c];
        *(ushort4*)&out[(size_t)(c0 + c) * R + r0 + tc] = w;
    }
}

// ---------------- fused LN3 + router ----------------
__global__ __launch_bounds__(256) void ln_router(
    const float* __restrict__ xin, const float* __restrict__ gw, const float* __restrict__ gb,
    const float* __restrict__ rw, const float* __restrict__ rb,
    const float* __restrict__ tmask, float* __restrict__ tln,
    int* __restrict__ eidx, float* __restrict__ gate, int* __restrict__ valid,
    float* __restrict__ partials)
{
    int wid = threadIdx.x >> 6, lane = threadIdx.x & 63;
    int tok = blockIdx.x * 4 + wid;
    __shared__ float wpart[4][10];

    const float* xrow = xin + (size_t)tok * DMODEL;
    float xv[16];
    float s = 0.f, ss = 0.f;
#pragma unroll
    for (int kk = 0; kk < 16; ++kk) {
        float x = xrow[lane + (kk << 6)];
        xv[kk] = x; s += x; ss += x * x;
    }
#pragma unroll
    for (int o = 1; o < 64; o <<= 1) { s += __shfl_xor(s, o, 64); ss += __shfl_xor(ss, o, 64); }
    float mean = s * (1.0f / DMODEL);
    float var  = ss * (1.0f / DMODEL) - mean * mean;
    float inv  = rsqrtf(var + 1e-5f);

    float acc[8] = {0,0,0,0,0,0,0,0};
#pragma unroll 4
    for (int kk = 0; kk < 16; ++kk) {
        int d = lane + (kk << 6);
        float xd = (xv[kk] - mean) * inv * gw[d] + gb[d];
        tln[(size_t)tok * DMODEL + d] = xd;
        const float4* rp = (const float4*)(rw + (size_t)d * 8);
        float4 r0 = rp[0], r1 = rp[1];
        acc[0] = fmaf(xd, r0.x, acc[0]); acc[1] = fmaf(xd, r0.y, acc[1]);
        acc[2] = fmaf(xd, r0.z, acc[2]); acc[3] = fmaf(xd, r0.w, acc[3]);
        acc[4] = fmaf(xd, r1.x, acc[4]); acc[5] = fmaf(xd, r1.y, acc[5]);
        acc[6] = fmaf(xd, r1.z, acc[6]); acc[7] = fmaf(xd, r1.w, acc[7]);
    }
#pragma unroll
    for (int e = 0; e < 8; ++e)
#pragma unroll
        for (int o = 1; o < 64; o <<= 1) acc[e] += __shfl_xor(acc[e], o, 64);

    if (lane == 0) {
        float l[8]; float m = -1e30f;
#pragma unroll
        for (int e = 0; e < 8; ++e) { l[e] = acc[e] + rb[e]; m = fmaxf(m, l[e]); }
        float se = 0.f;
#pragma unroll
        for (int e = 0; e < 8; ++e) se += expf(l[e] - m);
        int am = 0; float bm = l[0];
#pragma unroll
        for (int e = 1; e < 8; ++e) if (l[e] > bm) { bm = l[e]; am = e; }
        float inv_se = 1.0f / se;
        float g = expf(l[am] - m) * inv_se;
        float vld = (tmask[tok] > 0.f) ? 1.f : 0.f;
        eidx[tok] = am; gate[tok] = g; valid[tok] = (int)vld;
#pragma unroll
        for (int e = 0; e < 8; ++e) wpart[wid][e] = expf(l[e] - m) * inv_se * vld;
        float lse = logf(se) + m;
        wpart[wid][8] = lse * lse * vld;
        wpart[wid][9] = vld;
    }
    __syncthreads();
    if (threadIdx.x == 0) {
        for (int j = 0; j < 10; ++j)
            partials[blockIdx.x * 10 + j] = wpart[0][j] + wpart[1][j] + wpart[2][j] + wpart[3][j];
    }
}

// ---------------- capacity scan ----------------
__global__ __launch_bounds__(256) void scan_kernel(
    const int* __restrict__ eidx, const int* __restrict__ valid, const float* __restrict__ gate,
    int* __restrict__ pc, float* __restrict__ gk, int* __restrict__ keepf,
    int* __restrict__ counts)
{
    __shared__ int cnt[256][8];
    int tid = threadIdx.x;
    int local[8] = {0,0,0,0,0,0,0,0};
    int base = tid * 16;
    for (int i = 0; i < 16; ++i) { int e = eidx[base + i]; local[e] += valid[base + i]; }
#pragma unroll
    for (int e = 0; e < 8; ++e) cnt[tid][e] = local[e];
    __syncthreads();
    if (tid < 8) {
        int run = 0;
        for (int i = 0; i < 256; ++i) { int t = cnt[i][tid]; cnt[i][tid] = run; run += t; }
        counts[tid] = run;
    }
    __syncthreads();
    int off[8];
#pragma unroll
    for (int e = 0; e < 8; ++e) off[e] = cnt[tid][e];
    for (int i = 0; i < 16; ++i) {
        int tok = base + i;
        int e = eidx[tok], v = valid[tok];
        int pos = off[e]; off[e] += v;
        int kp = (v && pos < CAPE) ? 1 : 0;
        pc[tok]    = (pos < CAPE) ? pos : (CAPE - 1);
        keepf[tok] = kp;
        gk[tok]    = kp ? gate[tok] : 0.f;
    }
}

// ---------------- dispatch (expert-range) -> bf16 buffers ----------------
__global__ __launch_bounds__(256) void dispatch_bf16(const float* __restrict__ tln,
    const int* __restrict__ eidx, const int* __restrict__ pc, const int* __restrict__ keepf,
    unsigned short* __restrict__ buf, int e0, int ec)
{
    int tok = blockIdx.x;
    if (!keepf[tok]) return;
    int e = eidx[tok];
    if (e < e0 || e >= e0 + ec) return;
    int p = pc[tok];
    const float4 v = ((const float4*)(tln + (size_t)tok * DMODEL))[threadIdx.x];
    ushort4 o;
    o.x = f2bf(v.x); o.y = f2bf(v.y); o.z = f2bf(v.z); o.w = f2bf(v.w);
    ((ushort4*)(buf + ((size_t)(e - e0) * CAPE + p) * DMODEL))[threadIdx.x] = o;
}

// ---------------- combine add: out += gk * (ob0 + ob1) ----------------
__global__ __launch_bounds__(256) void combine_bf16(const unsigned short* __restrict__ ob,
    const int* __restrict__ eidx, const int* __restrict__ pc, const float* __restrict__ gk,
    float* __restrict__ out, int e0, int ec, long long sHalf)
{
    int tok = blockIdx.x;
    int e = eidx[tok];
    if (e < e0 || e >= e0 + ec) return;
    float g = gk[tok];
    int p = pc[tok];
    size_t idx = ((size_t)(e - e0) * CAPE + p) * DMODEL;
    float4* o = (float4*)(out + (size_t)tok * DMODEL);
    const ushort4 u0 = ((const ushort4*)(ob + idx))[threadIdx.x];
    const ushort4 u1 = ((const ushort4*)(ob + sHalf + idx))[threadIdx.x];
    float4 a = o[threadIdx.x];
    a.x += g * (bf2f(u0.x) + bf2f(u1.x));
    a.y += g * (bf2f(u0.y) + bf2f(u1.y));
    a.z += g * (bf2f(u0.z) + bf2f(u1.z));
    a.w += g * (bf2f(u0.w) + bf2f(u1.w));
    o[threadIdx.x] = a;
}

// ---------------- final scalar losses (1024 partials, 16/lane) ----------------
__global__ __launch_bounds__(64) void loss_kernel(const float* __restrict__ partials,
    const int* __restrict__ counts, float* __restrict__ out2)
{
    int lane = threadIdx.x;
    float p[10] = {0,0,0,0,0,0,0,0,0,0};
    for (int r = 0; r < 16; ++r) {
        const float* row = partials + ((size_t)lane * 16 + r) * 10;
#pragma unroll
        for (int j = 0; j < 10; ++j) p[j] += row[j];
    }
#pragma unroll
    for (int j = 0; j < 10; ++j)
#pragma unroll
        for (int o = 1; o < 64; o <<= 1) p[j] += __shfl_xor(p[j], o, 64);
    if (lane == 0) {
        float nv = fmaxf(p[9], 1.f);
        float lb = 0.f;
        for (int e = 0; e < 8; ++e) lb += ((float)counts[e] / nv) * (p[e] / nv);
        lb *= (float)NEXP;
        out2[0] = lb;
        out2[1] = p[8] / nv;
    }
}

// ---------------- host launch ----------------
extern "C" void kernel_launch(void* const* d_in, const int* in_sizes, int n_in,
                              void* d_out, int out_size, void* d_ws, size_t ws_size,
                              hipStream_t stream)
{
    const float* tgt        = (const float*)d_in[0];
    const float* src        = (const float*)d_in[1];
    const float* token_mask = (const float*)d_in[5];
    const float* ln1w = (const float*)d_in[6],  *ln1b = (const float*)d_in[7];
    const float* self_in_w  = (const float*)d_in[8],  *self_in_b  = (const float*)d_in[9];
    const float* self_out_w = (const float*)d_in[10], *self_out_b = (const float*)d_in[11];
    const float* ln2w = (const float*)d_in[12], *ln2b = (const float*)d_in[13];
    const float* enc_in_w   = (const float*)d_in[14], *enc_in_b   = (const float*)d_in[15];
    const float* enc_out_w  = (const float*)d_in[16], *enc_out_b  = (const float*)d_in[17];
    const float* ln3w = (const float*)d_in[18], *ln3b = (const float*)d_in[19];
    const float* rw = (const float*)d_in[20], *rb = (const float*)d_in[21];
    const float* w1 = (const float*)d_in[22], *b1 = (const float*)d_in[23];
    const float* w2 = (const float*)d_in[24], *b2 = (const float*)d_in[25];

    float* out = (float*)d_out;          // residual stream lives HERE
    float* ws  = (float*)d_ws;

    // ---- fixed layout (floats) ----
    float* tln = ws;                         // tln f16 single (2M floats used)
    float* ctx = ws + 4194304;               // ctx f16 single (2M floats used)
    int*   eidxA   = (int*)(ws + 8388608);
    int*   validA  = eidxA + 4096;
    int*   pcA     = validA + 4096;
    int*   keepA   = pcA + 4096;
    int*   countsA = keepA + 4096;           // 16
    float* gateA   = (float*)(countsA + 16);
    float* gkA     = gateA + 4096;
    float* partA   = gkA + 4096;             // 1024*10
    const size_t POOL_OFF = 8425984;         // floats
    float* pool = ws + POOL_OFF;

    size_t Wf = ws_size / sizeof(float);
    size_t pf = (Wf > POOL_OFF) ? (Wf - POOL_OFF) : 0;

    // pool (floats): qreg bg*786432 + vreg bg*262144 + sreg max(weights, zc*131072)
    int bg, zc;
    if      (pf >= 25165824) { bg = 8; zc = 128; }
    else if (pf >= 12582912) { bg = 8; zc = 32; }
    else if (pf >= 7340032)  { bg = 4; zc = 16; }
    else                     { bg = 2; zc = 16; }
    int ecs = 1;
    for (int c = 8; c >= 1; c >>= 1)
        if ((size_t)c * 4063232ull <= pf) { ecs = c; break; }
    int elog = (ecs == 8) ? 3 : (ecs == 4) ? 2 : (ecs == 2) ? 1 : 0;

    float* qreg = pool;
    float* vreg = qreg + (size_t)bg * 786432;
    float* sreg = vreg + (size_t)bg * 262144;

    h16* tlnh = (h16*)tln;
    h16* ctxh = (h16*)ctx;

    // ================= self attention =================
    ln_f16<<<NTOK, 256, 0, stream>>>(tgt, ln1w, ln1b, tlnh);

    for (int g0 = 0; g0 < BATCH; g0 += bg) {
        h16* sb = (h16*)sreg;
        h16* wf = sb;                               // self_in_w f16: 3,145,728 f16
        cvt_f16<<<1536, 256, 0, stream>>>(self_in_w, wf, 393216);

        h16* qkvh = (h16*)qreg;
        gemm_f16<<<dim3(24, bg * 4, 1), 256, 0, stream>>>(
            tlnh + (size_t)g0 * 524288, 1024, wf, 1024, self_in_b, qkvh, 1024, 3072);

        h16* vth = (h16*)vreg;
        vt_split<<<dim3(8, 1, bg * 16), 256, 0, stream>>>(qkvh + 2048, 3072, vth);

        h16* sh = sb;
        for (int c0 = 0; c0 < bg * 16; c0 += zc) {
            attn_qk<true><<<dim3(4, 4, zc), 256, 0, stream>>>(
                qkvh, 3072, qkvh + 1024, 3072, sh, c0);
            attn_pv<true><<<dim3(8, 1, zc), 512, 0, stream>>>(
                sh, vth + (size_t)c0 * 32768, ctxh, g0 * 16 + c0);
        }
    }
    {
        h16* sb = (h16*)sreg;
        h16* owhi = sb, *owlo = sb + 1048576;
        split_f16<<<512, 256, 0, stream>>>(self_out_w, owhi, owlo, 131072);
        gemm_f16x2_nt<<<dim3(8, 32, 1), 256, 0, stream>>>(
            ctxh, 1024, owhi, owlo, 1024, self_out_b, tgt, out, 1024, 1024);
    }

    // ================= cross attention =================
    ln_f16<<<NTOK, 256, 0, stream>>>(out, ln2w, ln2b, tlnh);

    for (int g0 = 0; g0 < BATCH; g0 += bg) {
        h16* sb = (h16*)sreg;
        h16* sf = sb;                               // src f16: bg*524288 f16
        h16* ef = sb + (size_t)bg * 524288;         // enc_in_w f16: 3,145,728 f16
        cvt_f16<<<bg * 256, 256, 0, stream>>>(src + (size_t)g0 * 524288, sf, bg * 65536);
        cvt_f16<<<1536, 256, 0, stream>>>(enc_in_w, ef, 393216);

        h16* q2h  = (h16*)qreg;
        h16* kv2h = q2h + (size_t)bg * 524288;
        gemm_f16<<<dim3(8, bg * 4, 1), 256, 0, stream>>>(
            tlnh + (size_t)g0 * 524288, 1024, ef, 1024, enc_in_b, q2h, 1024, 1024);
        gemm_f16<<<dim3(16, bg * 4, 1), 256, 0, stream>>>(
            sf, 1024, ef + 1048576, 1024, enc_in_b + 1024, kv2h, 1024, 2048);

        h16* vth = (h16*)vreg;
        vt_split<<<dim3(8, 1, bg * 16), 256, 0, stream>>>(kv2h + 1024, 2048, vth);

        h16* sh = sb;
        for (int c0 = 0; c0 < bg * 16; c0 += zc) {
            attn_qk<false><<<dim3(4, 4, zc), 256, 0, stream>>>(
                q2h, 1024, kv2h, 2048, sh, c0);
            attn_pv<false><<<dim3(8, 1, zc), 512, 0, stream>>>(
                sh, vth + (size_t)c0 * 32768, ctxh, g0 * 16 + c0);
        }
    }
    {
        h16* sb = (h16*)sreg;
        h16* owhi = sb, *owlo = sb + 1048576;
        split_f16<<<512, 256, 0, stream>>>(enc_out_w, owhi, owlo, 131072);
        gemm_f16x2_nt<<<dim3(8, 32, 1), 256, 0, stream>>>(
            ctxh, 1024, owhi, owlo, 1024, enc_out_b, out, out, 1024, 1024);
    }

    // ================= MoE =================
    ln_router<<<1024, 256, 0, stream>>>(out, ln3w, ln3b, rw, rb, token_mask, tln,
                                        eidxA, gateA, validA, partA);
    scan_kernel<<<1, 256, 0, stream>>>(eidxA, validA, gateA, pcA, gkA, keepA, countsA);

    long long sHalf = 0;
    for (int e0 = 0; e0 < NEXP; e0 += ecs) {
        unsigned short* wt   = (unsigned short*)pool;
        unsigned short* hB   = (unsigned short*)(pool + (size_t)ecs * 2097152);
        unsigned short* bufB = (unsigned short*)(pool + (size_t)ecs * 3407872);
        unsigned short* obB  = bufB;                       // ob0 overlays bufB
        sHalf = (long long)ecs * 655360;

        tcvt_kernel<<<dim3(64, 16, ecs), 256, 0, stream>>>(
            w1 + (size_t)e0 * 4194304, wt, 1024, 4096);
        dispatch_bf16<<<NTOK, 256, 0, stream>>>(tln, eidxA, pcA, keepA, bufB, e0, ecs);
        gemm_bf16_moe<128, true, true, 1><<<ecs * 5 * 32, 256, 0, stream>>>(
            bufB, wt, b1 + (size_t)e0 * 4096, hB,
            1024, 655360LL, 4194304LL, 2621440LL, 4096LL, 4096,
            ecs - 1, elog, 5, 32, countsA, e0, 0LL);

        tcvt_kernel<<<dim3(16, 64, ecs), 256, 0, stream>>>(
            w2 + (size_t)e0 * 4194304, wt, 4096, 1024);
        gemm_bf16_moe<64, false, false, 2><<<ecs * 5 * 16 * 2, 256, 0, stream>>>(
            hB, wt, b2 + (size_t)e0 * 1024, obB,
            4096, 2621440LL, 4194304LL, 655360LL, 1024LL, 1024,
            ecs - 1, elog, 5, 16, countsA, e0, sHalf);

        combine_bf16<<<NTOK, 256, 0, stream>>>(obB, eidxA, pcA, gkA, out, e0, ecs, sHalf);
    }

    // ===== losses =====
    loss_kernel<<<1, 64, 0, stream>>>(partA, countsA, out + (size_t)NTOK * DMODEL);
}

// Round 17
// 541.408 us; speedup vs baseline: 5.0000x; 1.0024x over previous
//
#include <hip/hip_runtime.h>
#include <cstdint>

// ---------------- problem constants ----------------
constexpr int BATCH  = 8;
constexpr int TSEQ   = 512;
constexpr int DMODEL = 1024;
constexpr int NEXP   = 8;
constexpr int CAPE   = 640;
constexpr int NTOK   = BATCH * TSEQ;        // 4096

typedef _Float16 h16;
typedef __attribute__((ext_vector_type(8))) short bfrag;
typedef __attribute__((ext_vector_type(8))) _Float16 hfrag;
typedef __attribute__((ext_vector_type(4))) float f32x4;

__device__ __forceinline__ unsigned short f2bf(float f) {
    uint32_t u = __float_as_uint(f);
    uint32_t r = (u + 0x7FFFu + ((u >> 16) & 1u)) >> 16;   // RNE
    return (unsigned short)r;
}
__device__ __forceinline__ float bf2f(unsigned short b) {
    return __uint_as_float((uint32_t)b << 16);
}

#define GLL16(SRC, DST) __builtin_amdgcn_global_load_lds( \
    (const __attribute__((address_space(1))) void*)(SRC), \
    (__attribute__((address_space(3))) void*)(DST), 16, 0, 0)

// ---------------- LayerNorm -> single f16 ----------------
__global__ __launch_bounds__(256) void ln_f16(const float* __restrict__ in,
    const float* __restrict__ gw, const float* __restrict__ gb,
    h16* __restrict__ oh)
{
    int row = blockIdx.x, tid = threadIdx.x;
    const float4 v = *(const float4*)(in + (size_t)row * DMODEL + tid * 4);
    float s  = v.x + v.y + v.z + v.w;
    float ss = v.x*v.x + v.y*v.y + v.z*v.z + v.w*v.w;
#pragma unroll
    for (int o = 1; o < 64; o <<= 1) { s += __shfl_xor(s, o, 64); ss += __shfl_xor(ss, o, 64); }
    __shared__ float rs[4], rss[4];
    int wid = tid >> 6, lane = tid & 63;
    if (lane == 0) { rs[wid] = s; rss[wid] = ss; }
    __syncthreads();
    s  = rs[0] + rs[1] + rs[2] + rs[3];
    ss = rss[0] + rss[1] + rss[2] + rss[3];
    float mean = s * (1.0f / DMODEL);
    float var  = ss * (1.0f / DMODEL) - mean * mean;
    float inv  = rsqrtf(var + 1e-5f);
    float4 w4 = *(const float4*)(gw + tid * 4);
    float4 b4 = *(const float4*)(gb + tid * 4);
    short4 hv;
    ((h16*)&hv)[0] = (h16)((v.x - mean) * inv * w4.x + b4.x);
    ((h16*)&hv)[1] = (h16)((v.y - mean) * inv * w4.y + b4.y);
    ((h16*)&hv)[2] = (h16)((v.z - mean) * inv * w4.z + b4.z);
    ((h16*)&hv)[3] = (h16)((v.w - mean) * inv * w4.w + b4.w);
    *(short4*)(oh + (size_t)row * DMODEL + tid * 4) = hv;
}

// ---------------- fp32 -> f16 single convert ----------------
__global__ __launch_bounds__(256) void cvt_f16(const float* __restrict__ in,
    h16* __restrict__ out, int n8)
{
    int i = blockIdx.x * 256 + threadIdx.x;
    if (i >= n8) return;
    const float4* p = (const float4*)in + 2 * (size_t)i;
    float4 v0 = p[0], v1 = p[1];
    float vv[8] = {v0.x, v0.y, v0.z, v0.w, v1.x, v1.y, v1.z, v1.w};
    hfrag h;
#pragma unroll
    for (int j = 0; j < 8; ++j) h[j] = (h16)vv[j];
    ((hfrag*)out)[i] = h;
}

// ---------------- fp32 -> fp16 hi/lo split (out-proj weights) ----------------
__global__ __launch_bounds__(256) void split_f16(const float* __restrict__ in,
    h16* __restrict__ hi, h16* __restrict__ lo, int n8)
{
    int i = blockIdx.x * 256 + threadIdx.x;
    if (i >= n8) return;
    const float4* p = (const float4*)in + 2 * (size_t)i;
    float4 v0 = p[0], v1 = p[1];
    float vv[8] = {v0.x, v0.y, v0.z, v0.w, v1.x, v1.y, v1.z, v1.w};
    hfrag h, l;
#pragma unroll
    for (int j = 0; j < 8; ++j) {
        h16 hj = (h16)vv[j];
        h[j] = hj;
        l[j] = (h16)(vv[j] - (float)hj);
    }
    ((hfrag*)hi)[i] = h;
    ((hfrag*)lo)[i] = l;
}

// ---------------- pure-f16 1-product NT GEMM, BK=128, f16 out + bias ----------------
__global__ __launch_bounds__(256) void gemm_f16(
    const h16* __restrict__ A, int lda,
    const h16* __restrict__ B, int ldb,
    const float* __restrict__ bias,
    h16* __restrict__ Cf, int K, int ldc)
{
    __shared__ h16 AL[16384], BL[16384];   // 128x128 f16 each, 64 KB
    int rowBase = blockIdx.y * 128, colBase = blockIdx.x * 128;
    int t = threadIdx.x, lane = t & 63, wid = t >> 6;
    int wr = (wid >> 1) * 64, wc = (wid & 1) * 64;
    const h16* Ag = A + (size_t)rowBase * lda;
    const h16* Bg = B + (size_t)colBase * ldb;
    f32x4 acc[4][4] = {};
    int l15 = lane & 15, g = lane >> 4;

    for (int k0 = 0; k0 < K; k0 += 128) {
        __syncthreads();
#pragma unroll
        for (int cc = 0; cc < 8; ++cc) {
            int c = t + cc * 256;
            int r = c >> 4, sq = (c & 15) ^ (r & 15);
            GLL16(Ag + (size_t)r * lda + k0 + sq * 8, &AL[c * 8]);
            GLL16(Bg + (size_t)r * ldb + k0 + sq * 8, &BL[c * 8]);
        }
        __syncthreads();

#pragma unroll
        for (int kk = 0; kk < 4; ++kk) {
            hfrag bv[4];
#pragma unroll
            for (int n = 0; n < 4; ++n) {
                int rr = wc + n * 16 + l15;
                int q = ((kk << 2) | g) ^ (rr & 15);
                bv[n] = *(const hfrag*)&BL[rr * 128 + q * 8];
            }
#pragma unroll
            for (int m = 0; m < 4; ++m) {
                int rr = wr + m * 16 + l15;
                int q = ((kk << 2) | g) ^ (rr & 15);
                hfrag a = *(const hfrag*)&AL[rr * 128 + q * 8];
#pragma unroll
                for (int n = 0; n < 4; ++n)
                    acc[m][n] = __builtin_amdgcn_mfma_f32_16x16x32_f16(a, bv[n], acc[m][n], 0, 0, 0);
            }
        }
    }

    int g4 = g * 4;
#pragma unroll
    for (int m = 0; m < 4; ++m) {
        int row0 = rowBase + wr + m * 16 + g4;
#pragma unroll
        for (int n = 0; n < 4; ++n) {
            int col = colBase + wc + n * 16 + l15;
            float bv = bias[col];
#pragma unroll
            for (int j = 0; j < 4; ++j)
                Cf[(size_t)(row0 + j) * ldc + col] = (h16)(acc[m][n][j] + bv);
        }
    }
}

// ---------------- fp16 split NT MFMA GEMM (out-proj), BK=64, A single, B hi/lo ----------------
__global__ __launch_bounds__(256) void gemm_f16x2_nt(
    const h16* __restrict__ Ahi, int lda,
    const h16* __restrict__ Bhi, const h16* __restrict__ Blo, int ldb,
    const float* __restrict__ bias, const float* __restrict__ res,
    float* __restrict__ C, int K, int ldc)
{
    __shared__ h16 AhL[8192], BhL[8192], BlL[8192];
    int rowBase = blockIdx.y * 128, colBase = blockIdx.x * 128;
    int t = threadIdx.x, lane = t & 63, wid = t >> 6;
    int wr = (wid >> 1) * 64, wc = (wid & 1) * 64;
    const h16* Ah = Ahi + (size_t)rowBase * lda;
    const h16* Bh = Bhi + (size_t)colBase * ldb;
    const h16* Bl = Blo + (size_t)colBase * ldb;
    f32x4 acc[4][4] = {};
    int l15 = lane & 15, g = lane >> 4;

    for (int k0 = 0; k0 < K; k0 += 64) {
        __syncthreads();
#pragma unroll
        for (int cc = 0; cc < 4; ++cc) {
            int c = t + cc * 256;
            int r = c >> 3, sq = (c & 7) ^ (r & 7);
            GLL16(Ah + (size_t)r * lda + k0 + sq * 8, &AhL[c * 8]);
            GLL16(Bh + (size_t)r * ldb + k0 + sq * 8, &BhL[c * 8]);
            GLL16(Bl + (size_t)r * ldb + k0 + sq * 8, &BlL[c * 8]);
        }
        __syncthreads();

#pragma unroll
        for (int kk = 0; kk < 2; ++kk) {
            hfrag bh[4], bl[4];
#pragma unroll
            for (int n = 0; n < 4; ++n) {
                int rr = wc + n * 16 + l15;
                int q = ((kk << 2) | g) ^ (rr & 7);
                bh[n] = *(const hfrag*)&BhL[rr * 64 + q * 8];
                bl[n] = *(const hfrag*)&BlL[rr * 64 + q * 8];
            }
#pragma unroll
            for (int m = 0; m < 4; ++m) {
                int rr = wr + m * 16 + l15;
                int q = ((kk << 2) | g) ^ (rr & 7);
                hfrag ah = *(const hfrag*)&AhL[rr * 64 + q * 8];
#pragma unroll
                for (int n = 0; n < 4; ++n) {
                    acc[m][n] = __builtin_amdgcn_mfma_f32_16x16x32_f16(ah, bh[n], acc[m][n], 0, 0, 0);
                    acc[m][n] = __builtin_amdgcn_mfma_f32_16x16x32_f16(ah, bl[n], acc[m][n], 0, 0, 0);
                }
            }
        }
    }

    int g4 = g * 4;
#pragma unroll
    for (int m = 0; m < 4; ++m) {
        int row0 = rowBase + wr + m * 16 + g4;
#pragma unroll
        for (int n = 0; n < 4; ++n) {
            int col = colBase + wc + n * 16 + l15;
            float bv = bias[col];
#pragma unroll
            for (int j = 0; j < 4; ++j) {
                float v = acc[m][n][j] + bv + res[(size_t)(row0 + j) * ldc + col];
                C[(size_t)(row0 + j) * ldc + col] = v;
            }
        }
    }
}

// ---------------- attention QK^T (pure f16 1-product, K=64 single step) ----------------
template<bool CAUSAL>
__global__ __launch_bounds__(256) void attn_qk(
    const h16* __restrict__ Q, int lda,
    const h16* __restrict__ Km, int ldb,
    h16* __restrict__ Sh, int zoff)
{
    int rowBase = blockIdx.y * 128, colBase = blockIdx.x * 128;
    if (CAUSAL && colBase >= rowBase + 128) return;
    __shared__ h16 AL[8192], BL[8192];
    int z = blockIdx.z;
    int bh_ = zoff + z, b = bh_ >> 4, h = bh_ & 15;
    const h16* Ag = Q  + (size_t)(b * 512 + rowBase) * lda + h * 64;
    const h16* Bg = Km + (size_t)(b * 512 + colBase) * ldb + h * 64;
    int t = threadIdx.x, lane = t & 63, wid = t >> 6;
    int wr = (wid >> 1) * 64, wc = (wid & 1) * 64;
    f32x4 acc[4][4] = {};
    int l15 = lane & 15, g = lane >> 4;

#pragma unroll
    for (int cc = 0; cc < 4; ++cc) {
        int c = t + cc * 256;
        int r = c >> 3, sq = (c & 7) ^ (r & 7);
        GLL16(Ag + (size_t)r * lda + sq * 8, &AL[c * 8]);
        GLL16(Bg + (size_t)r * ldb + sq * 8, &BL[c * 8]);
    }
    __syncthreads();

#pragma unroll
    for (int kk = 0; kk < 2; ++kk) {
        hfrag bv[4];
#pragma unroll
        for (int n = 0; n < 4; ++n) {
            int rr = wc + n * 16 + l15;
            int q = ((kk << 2) | g) ^ (rr & 7);
            bv[n] = *(const hfrag*)&BL[rr * 64 + q * 8];
        }
#pragma unroll
        for (int m = 0; m < 4; ++m) {
            int rr = wr + m * 16 + l15;
            int q = ((kk << 2) | g) ^ (rr & 7);
            hfrag a = *(const hfrag*)&AL[rr * 64 + q * 8];
#pragma unroll
            for (int n = 0; n < 4; ++n)
                acc[m][n] = __builtin_amdgcn_mfma_f32_16x16x32_f16(a, bv[n], acc[m][n], 0, 0, 0);
        }
    }

    size_t sbase = (size_t)z * 262144;
    int g4 = g * 4;
#pragma unroll
    for (int m = 0; m < 4; ++m) {
        int row0 = rowBase + wr + m * 16 + g4;
#pragma unroll
        for (int n = 0; n < 4; ++n) {
            int col = colBase + wc + n * 16 + l15;
#pragma unroll
            for (int j = 0; j < 4; ++j)
                Sh[sbase + (size_t)(row0 + j) * 512 + col] = (h16)(acc[m][n][j] * 0.125f);
        }
    }
}

// ---------------- fused softmax+PV: 512 threads, in-block K-split, P single f16 ----------------
template<bool CAUSAL>
__global__ __launch_bounds__(512) void attn_pv(
    const h16* __restrict__ Shg,
    const h16* __restrict__ Vh,
    h16* __restrict__ Ch, int bh0)
{
    __shared__ h16 ShL[2][4096], VhL[2][4096];
    __shared__ float red[256][16];
    __shared__ float mS[64], iS[64];
    int z = blockIdx.z, bh_ = bh0 + z;
    int rowBase = blockIdx.x * 64;
    const h16* Sa = Shg + (size_t)z * 262144 + (size_t)rowBase * 512;
    const h16* Va = Vh + (size_t)z * 32768;
    int t = threadIdx.x;
    int wv = t >> 6, lane = t & 63;
    int g2 = wv >> 2, wid = wv & 3, tl = t & 255;
    int l15 = lane & 15, g = lane >> 4;

    {
        int tr = t >> 3, tq = t & 7;
        int limit = CAUSAL ? (rowBase + tr + 1) : 512;
        float m = -1e30f, l = 0.f;
        const h16* rh = Sa + (size_t)tr * 512;
        for (int c = 0; c < 8; ++c) {
            int col0 = tq * 8 + c * 64;
            if (col0 >= limit) break;
            hfrag hv = *(const hfrag*)(rh + col0);
            float s[8]; float cm = -1e30f;
#pragma unroll
            for (int j = 0; j < 8; ++j) {
                float sv = (float)hv[j];
                s[j] = (col0 + j < limit) ? sv : -1e30f;
                cm = fmaxf(cm, s[j]);
            }
            if (cm > m) { l *= __expf(m - cm); m = cm; }
#pragma unroll
            for (int j = 0; j < 8; ++j) l += __expf(s[j] - m);
        }
#pragma unroll
        for (int o = 1; o < 8; o <<= 1) {
            float mo = __shfl_xor(m, o, 64);
            float lo2 = __shfl_xor(l, o, 64);
            float mc = fmaxf(m, mo);
            l = l * __expf(m - mc) + lo2 * __expf(mo - mc);
            m = mc;
        }
        if (tq == 0) { mS[tr] = m; iS[tr] = 1.0f / l; }
    }
    __syncthreads();

    int arow = wid * 16 + l15;
    float am = mS[arow], ai = iS[arow];
    int alim = CAUSAL ? (rowBase + arow + 1) : 512;
    int kend = CAUSAL ? (rowBase + 64) : 512;
    int nck = kend >> 6;
    f32x4 acc[4] = {};

    for (int ci = 0; ci < nck; ci += 2) {
        int myck = ci + g2;
        bool act = myck < nck;
        int k0 = myck << 6;
        __syncthreads();
        if (act) {
#pragma unroll
            for (int cc = 0; cc < 2; ++cc) {
                int c = tl + cc * 256;
                int r = c >> 3, sq = (c & 7) ^ (r & 7);
                GLL16(Sa + (size_t)r * 512 + k0 + sq * 8, &ShL[g2][c * 8]);
                GLL16(Va + (size_t)r * 512 + k0 + sq * 8, &VhL[g2][c * 8]);
            }
        }
        __syncthreads();
        if (act) {
#pragma unroll
            for (int kk = 0; kk < 2; ++kk) {
                int chunk = (kk << 2) | g;
                int aq = chunk ^ (arow & 7);
                hfrag sh_ = *(const hfrag*)&ShL[g2][arow * 64 + aq * 8];
                int cbase = k0 + chunk * 8;
                hfrag ph;
#pragma unroll
                for (int j = 0; j < 8; ++j) {
                    float p = __expf((float)sh_[j] - am) * ai;
                    ph[j] = (h16)((cbase + j < alim) ? p : 0.f);
                }
#pragma unroll
                for (int n = 0; n < 4; ++n) {
                    int brow = n * 16 + l15;
                    int bq = chunk ^ (brow & 7);
                    hfrag bh = *(const hfrag*)&VhL[g2][brow * 64 + bq * 8];
                    acc[n] = __builtin_amdgcn_mfma_f32_16x16x32_f16(ph, bh, acc[n], 0, 0, 0);
                }
            }
        }
    }

    __syncthreads();
    if (g2 == 1) {
#pragma unroll
        for (int n = 0; n < 4; ++n)
#pragma unroll
            for (int j = 0; j < 4; ++j) red[tl][n * 4 + j] = acc[n][j];
    }
    __syncthreads();
    if (g2 == 0) {
        int brow = (bh_ >> 4) * 512 + rowBase + wid * 16 + g * 4;
        int bcol = (bh_ & 15) * 64;
#pragma unroll
        for (int n = 0; n < 4; ++n) {
            int col = bcol + n * 16 + l15;
#pragma unroll
            for (int j = 0; j < 4; ++j)
                Ch[(size_t)(brow + j) * 1024 + col] = (h16)(acc[n][j] + red[tl][n * 4 + j]);
        }
    }
}

// ---------------- V-transpose (single plane) ----------------
__global__ __launch_bounds__(256) void vt_split(
    const h16* __restrict__ inh, int ld, h16* __restrict__ oh)
{
    __shared__ h16 tile[64][68];
    int z = blockIdx.z, b = z >> 4, h = z & 15;
    size_t ibase = ((size_t)b * 512 + blockIdx.x * 64) * ld + h * 64;
    size_t obase = (size_t)z * 32768 + blockIdx.x * 64;
    int tr = threadIdx.x >> 4, tc = (threadIdx.x & 15) * 4;
#pragma unroll
    for (int i = 0; i < 4; ++i) {
        int tt = tr + i * 16;
        short4 v = *(const short4*)(inh + ibase + (size_t)tt * ld + tc);
        tile[tt][tc + 0] = ((h16*)&v)[0];
        tile[tt][tc + 1] = ((h16*)&v)[1];
        tile[tt][tc + 2] = ((h16*)&v)[2];
        tile[tt][tc + 3] = ((h16*)&v)[3];
    }
    __syncthreads();
#pragma unroll
    for (int i = 0; i < 4; ++i) {
        int d = tr + i * 16;
        h16 w[4] = {tile[tc + 0][d], tile[tc + 1][d], tile[tc + 2][d], tile[tc + 3][d]};
        *(short4*)(oh + obase + (size_t)d * 512 + tc) = *(short4*)w;
    }
}

// ---------------- bf16 NT MFMA GEMM (MoE), BK=64, flat grid, XCD pinned, K-split, count-skip ----
template<int TN, bool RELU, bool ROWFAST, int KS>
__global__ __launch_bounds__(256) void gemm_bf16_moe(
    const unsigned short* __restrict__ A,
    const unsigned short* __restrict__ Bt,
    const float* __restrict__ bias,
    unsigned short* __restrict__ C,
    int K, long long sA, long long sB, long long sC, long long sBias, int ldc,
    int emask, int elog, int nrow, int ncol,
    const int* __restrict__ counts, int e0, long long sHalf)
{
    constexpr int NFR = TN / 32;
    __shared__ unsigned short Al[128 * 64];
    __shared__ unsigned short Bl[TN * 64];
    int id = blockIdx.x;
    int e = id & emask;
    int tb = id >> elog;
    int half = 0;
    if (KS == 2) {
        int per = nrow * ncol;
        half = (tb >= per) ? 1 : 0;
        tb -= half * per;
    }
    int row, col;
    if (ROWFAST) { row = tb % nrow; col = tb / nrow; }
    else         { col = tb % ncol; row = tb / ncol; }
    int rowBase = row * 128;

    int bound = counts[e0 + e];
    if (bound > CAPE) bound = CAPE;
    if (rowBase >= bound) return;

    A    += (size_t)e * sA;
    Bt   += (size_t)e * sB;
    bias += (size_t)e * sBias;
    long long zC = (long long)e * sC + (long long)half * sHalf;

    int colBase = col * TN;
    int t = threadIdx.x, lane = t & 63, wid = t >> 6;
    int wr = (wid >> 1) * 64, wc = (wid & 1) * (TN / 2);

    const unsigned short* Ag = A  + (size_t)rowBase * K;
    const unsigned short* Bg = Bt + (size_t)colBase * K;

    f32x4 acc[4][NFR] = {};
    int l15 = lane & 15, g = lane >> 4;

    int kb = half * (K / KS), ke = kb + (K / KS);
    for (int k0 = kb; k0 < ke; k0 += 64) {
        __syncthreads();
#pragma unroll
        for (int cc = 0; cc < 4; ++cc) {
            int c = t + cc * 256;
            int r = c >> 3, sq = (c & 7) ^ (r & 7);
            GLL16(Ag + (size_t)r * K + k0 + sq * 8, &Al[c * 8]);
        }
#pragma unroll
        for (int cc = 0; cc < TN / 32; ++cc) {
            int c = t + cc * 256;
            int r = c >> 3, sq = (c & 7) ^ (r & 7);
            GLL16(Bg + (size_t)r * K + k0 + sq * 8, &Bl[c * 8]);
        }
        __syncthreads();

        bfrag b[2][NFR];
#pragma unroll
        for (int kk = 0; kk < 2; ++kk)
#pragma unroll
            for (int n = 0; n < NFR; ++n) {
                int rr = wc + n * 16 + l15;
                int q = ((kk << 2) | g) ^ (rr & 7);
                b[kk][n] = *(const bfrag*)&Bl[rr * 64 + q * 8];
            }
#pragma unroll
        for (int m = 0; m < 4; ++m) {
            int rr = wr + m * 16 + l15;
#pragma unroll
            for (int kk = 0; kk < 2; ++kk) {
                int q = ((kk << 2) | g) ^ (rr & 7);
                bfrag a = *(const bfrag*)&Al[rr * 64 + q * 8];
#pragma unroll
                for (int n = 0; n < NFR; ++n)
                    acc[m][n] = __builtin_amdgcn_mfma_f32_16x16x32_bf16(a, b[kk][n], acc[m][n], 0, 0, 0);
            }
        }
    }

    int g4 = g * 4;
#pragma unroll
    for (int m = 0; m < 4; ++m) {
        int row0 = rowBase + wr + m * 16 + g4;
#pragma unroll
        for (int n = 0; n < NFR; ++n) {
            int cc = colBase + wc + n * 16 + l15;
            float bv = (KS == 1 || half == 0) ? bias[cc] : 0.f;
#pragma unroll
            for (int j = 0; j < 4; ++j) {
                float v = acc[m][n][j] + bv;
                if (RELU) v = fmaxf(v, 0.f);
                C[zC + (size_t)(row0 + j) * ldc + cc] = f2bf(v);
            }
        }
    }
}

// ---------------- transpose+convert fp32 [R][Cn] -> bf16 [Cn][R] (per z) ----------------
__global__ __launch_bounds__(256) void tcvt_kernel(const float* __restrict__ in,
    unsigned short* __restrict__ out, int R, int Cn)
{
    __shared__ unsigned short tile[64][68];
    size_t zoff = (size_t)blockIdx.z * R * Cn;
    in += zoff; out += zoff;
    int r0 = blockIdx.y * 64, c0 = blockIdx.x * 64;
    int tr = threadIdx.x >> 4, tc = (threadIdx.x & 15) * 4;
#pragma unroll
    for (int i = 0; i < 4; ++i) {
        int r = tr + i * 16;
        float4 v = *(const float4*)&in[(size_t)(r0 + r) * Cn + c0 + tc];
        tile[r][tc + 0] = f2bf(v.x);
        tile[r][tc + 1] = f2bf(v.y);
        tile[r][tc + 2] = f2bf(v.z);
        tile[r][tc + 3] = f2bf(v.w);
    }
    __syncthreads();
#pragma unroll
    for (int i = 0; i < 4; ++i) {
        int c = tr + i * 16;
        ushort4 w;
        w.x = tile[tc + 0][c];
        w.y = tile[tc + 1][c];
        w.z = tile[tc + 2][c];
        w.w = tile[tc + 3][c];
        *(ushort4*)&out[(size_t)(c0 + c) * R + r0 + tc] = w;
    }
}

// ---------------- fused LN3 + router ----------------
__global__ __launch_bounds__(256) void ln_router(
    const float* __restrict__ xin, const float* __restrict__ gw, const float* __restrict__ gb,
    const float* __restrict__ rw, const float* __restrict__ rb,
    const float* __restrict__ tmask, float* __restrict__ tln,
    int* __restrict__ eidx, float* __restrict__ gate, int* __restrict__ valid,
    float* __restrict__ partials)
{
    int wid = threadIdx.x >> 6, lane = threadIdx.x & 63;
    int tok = blockIdx.x * 4 + wid;
    __shared__ float wpart[4][10];

    const float* xrow = xin + (size_t)tok * DMODEL;
    float xv[16];
    float s = 0.f, ss = 0.f;
#pragma unroll
    for (int kk = 0; kk < 16; ++kk) {
        float x = xrow[lane + (kk << 6)];
        xv[kk] = x; s += x; ss += x * x;
    }
#pragma unroll
    for (int o = 1; o < 64; o <<= 1) { s += __shfl_xor(s, o, 64); ss += __shfl_xor(ss, o, 64); }
    float mean = s * (1.0f / DMODEL);
    float var  = ss * (1.0f / DMODEL) - mean * mean;
    float inv  = rsqrtf(var + 1e-5f);

    float acc[8] = {0,0,0,0,0,0,0,0};
#pragma unroll 4
    for (int kk = 0; kk < 16; ++kk) {
        int d = lane + (kk << 6);
        float xd = (xv[kk] - mean) * inv * gw[d] + gb[d];
        tln[(size_t)tok * DMODEL + d] = xd;
        const float4* rp = (const float4*)(rw + (size_t)d * 8);
        float4 r0 = rp[0], r1 = rp[1];
        acc[0] = fmaf(xd, r0.x, acc[0]); acc[1] = fmaf(xd, r0.y, acc[1]);
        acc[2] = fmaf(xd, r0.z, acc[2]); acc[3] = fmaf(xd, r0.w, acc[3]);
        acc[4] = fmaf(xd, r1.x, acc[4]); acc[5] = fmaf(xd, r1.y, acc[5]);
        acc[6] = fmaf(xd, r1.z, acc[6]); acc[7] = fmaf(xd, r1.w, acc[7]);
    }
#pragma unroll
    for (int e = 0; e < 8; ++e)
#pragma unroll
        for (int o = 1; o < 64; o <<= 1) acc[e] += __shfl_xor(acc[e], o, 64);

    if (lane == 0) {
        float l[8]; float m = -1e30f;
#pragma unroll
        for (int e = 0; e < 8; ++e) { l[e] = acc[e] + rb[e]; m = fmaxf(m, l[e]); }
        float se = 0.f;
#pragma unroll
        for (int e = 0; e < 8; ++e) se += expf(l[e] - m);
        int am = 0; float bm = l[0];
#pragma unroll
        for (int e = 1; e < 8; ++e) if (l[e] > bm) { bm = l[e]; am = e; }
        float inv_se = 1.0f / se;
        float g = expf(l[am] - m) * inv_se;
        float vld = (tmask[tok] > 0.f) ? 1.f : 0.f;
        eidx[tok] = am; gate[tok] = g; valid[tok] = (int)vld;
#pragma unroll
        for (int e = 0; e < 8; ++e) wpart[wid][e] = expf(l[e] - m) * inv_se * vld;
        float lse = logf(se) + m;
        wpart[wid][8] = lse * lse * vld;
        wpart[wid][9] = vld;
    }
    __syncthreads();
    if (threadIdx.x == 0) {
        for (int j = 0; j < 10; ++j)
            partials[blockIdx.x * 10 + j] = wpart[0][j] + wpart[1][j] + wpart[2][j] + wpart[3][j];
    }
}

// ---------------- capacity scan ----------------
__global__ __launch_bounds__(256) void scan_kernel(
    const int* __restrict__ eidx, const int* __restrict__ valid, const float* __restrict__ gate,
    int* __restrict__ pc, float* __restrict__ gk, int* __restrict__ keepf,
    int* __restrict__ counts)
{
    __shared__ int cnt[256][8];
    int tid = threadIdx.x;
    int local[8] = {0,0,0,0,0,0,0,0};
    int base = tid * 16;
    for (int i = 0; i < 16; ++i) { int e = eidx[base + i]; local[e] += valid[base + i]; }
#pragma unroll
    for (int e = 0; e < 8; ++e) cnt[tid][e] = local[e];
    __syncthreads();
    if (tid < 8) {
        int run = 0;
        for (int i = 0; i < 256; ++i) { int t = cnt[i][tid]; cnt[i][tid] = run; run += t; }
        counts[tid] = run;
    }
    __syncthreads();
    int off[8];
#pragma unroll
    for (int e = 0; e < 8; ++e) off[e] = cnt[tid][e];
    for (int i = 0; i < 16; ++i) {
        int tok = base + i;
        int e = eidx[tok], v = valid[tok];
        int pos = off[e]; off[e] += v;
        int kp = (v && pos < CAPE) ? 1 : 0;
        pc[tok]    = (pos < CAPE) ? pos : (CAPE - 1);
        keepf[tok] = kp;
        gk[tok]    = kp ? gate[tok] : 0.f;
    }
}

// ---------------- dispatch (expert-range) -> bf16 buffers ----------------
__global__ __launch_bounds__(256) void dispatch_bf16(const float* __restrict__ tln,
    const int* __restrict__ eidx, const int* __restrict__ pc, const int* __restrict__ keepf,
    unsigned short* __restrict__ buf, int e0, int ec)
{
    int tok = blockIdx.x;
    if (!keepf[tok]) return;
    int e = eidx[tok];
    if (e < e0 || e >= e0 + ec) return;
    int p = pc[tok];
    const float4 v = ((const float4*)(tln + (size_t)tok * DMODEL))[threadIdx.x];
    ushort4 o;
    o.x = f2bf(v.x); o.y = f2bf(v.y); o.z = f2bf(v.z); o.w = f2bf(v.w);
    ((ushort4*)(buf + ((size_t)(e - e0) * CAPE + p) * DMODEL))[threadIdx.x] = o;
}

// ---------------- combine add: out += gk * (ob0 + ob1) ----------------
__global__ __launch_bounds__(256) void combine_bf16(const unsigned short* __restrict__ ob,
    const int* __restrict__ eidx, const int* __restrict__ pc, const float* __restrict__ gk,
    float* __restrict__ out, int e0, int ec, long long sHalf)
{
    int tok = blockIdx.x;
    int e = eidx[tok];
    if (e < e0 || e >= e0 + ec) return;
    float g = gk[tok];
    int p = pc[tok];
    size_t idx = ((size_t)(e - e0) * CAPE + p) * DMODEL;
    float4* o = (float4*)(out + (size_t)tok * DMODEL);
    const ushort4 u0 = ((const ushort4*)(ob + idx))[threadIdx.x];
    const ushort4 u1 = ((const ushort4*)(ob + sHalf + idx))[threadIdx.x];
    float4 a = o[threadIdx.x];
    a.x += g * (bf2f(u0.x) + bf2f(u1.x));
    a.y += g * (bf2f(u0.y) + bf2f(u1.y));
    a.z += g * (bf2f(u0.z) + bf2f(u1.z));
    a.w += g * (bf2f(u0.w) + bf2f(u1.w));
    o[threadIdx.x] = a;
}

// ---------------- final scalar losses (1024 partials, 16/lane) ----------------
__global__ __launch_bounds__(64) void loss_kernel(const float* __restrict__ partials,
    const int* __restrict__ counts, float* __restrict__ out2)
{
    int lane = threadIdx.x;
    float p[10] = {0,0,0,0,0,0,0,0,0,0};
    for (int r = 0; r < 16; ++r) {
        const float* row = partials + ((size_t)lane * 16 + r) * 10;
#pragma unroll
        for (int j = 0; j < 10; ++j) p[j] += row[j];
    }
#pragma unroll
    for (int j = 0; j < 10; ++j)
#pragma unroll
        for (int o = 1; o < 64; o <<= 1) p[j] += __shfl_xor(p[j], o, 64);
    if (lane == 0) {
        float nv = fmaxf(p[9], 1.f);
        float lb = 0.f;
        for (int e = 0; e < 8; ++e) lb += ((float)counts[e] / nv) * (p[e] / nv);
        lb *= (float)NEXP;
        out2[0] = lb;
        out2[1] = p[8] / nv;
    }
}

// ---------------- host launch ----------------
extern "C" void kernel_launch(void* const* d_in, const int* in_sizes, int n_in,
                              void* d_out, int out_size, void* d_ws, size_t ws_size,
                              hipStream_t stream)
{
    const float* tgt        = (const float*)d_in[0];
    const float* src        = (const float*)d_in[1];
    const float* token_mask = (const float*)d_in[5];
    const float* ln1w = (const float*)d_in[6],  *ln1b = (const float*)d_in[7];
    const float* self_in_w  = (const float*)d_in[8],  *self_in_b  = (const float*)d_in[9];
    const float* self_out_w = (const float*)d_in[10], *self_out_b = (const float*)d_in[11];
    const float* ln2w = (const float*)d_in[12], *ln2b = (const float*)d_in[13];
    const float* enc_in_w   = (const float*)d_in[14], *enc_in_b   = (const float*)d_in[15];
    const float* enc_out_w  = (const float*)d_in[16], *enc_out_b  = (const float*)d_in[17];
    const float* ln3w = (const float*)d_in[18], *ln3b = (const float*)d_in[19];
    const float* rw = (const float*)d_in[20], *rb = (const float*)d_in[21];
    const float* w1 = (const float*)d_in[22], *b1 = (const float*)d_in[23];
    const float* w2 = (const float*)d_in[24], *b2 = (const float*)d_in[25];

    float* out = (float*)d_out;          // residual stream lives HERE
    float* ws  = (float*)d_ws;

    // ---- fixed layout (floats) ----
    float* tln = ws;                         // tln f16 single (2M floats used)
    float* ctx = ws + 4194304;               // ctx f16 single (2M floats used)
    int*   eidxA   = (int*)(ws + 8388608);
    int*   validA  = eidxA + 4096;
    int*   pcA     = validA + 4096;
    int*   keepA   = pcA + 4096;
    int*   countsA = keepA + 4096;           // 16
    float* gateA   = (float*)(countsA + 16);
    float* gkA     = gateA + 4096;
    float* partA   = gkA + 4096;             // 1024*10
    const size_t POOL_OFF = 8425984;         // floats
    float* pool = ws + POOL_OFF;

    size_t Wf = ws_size / sizeof(float);
    size_t pf = (Wf > POOL_OFF) ? (Wf - POOL_OFF) : 0;

    // pool (floats): qreg bg*786432 + vreg bg*262144 + sreg max(weights, zc*131072)
    int bg, zc;
    if      (pf >= 25165824) { bg = 8; zc = 128; }
    else if (pf >= 12582912) { bg = 8; zc = 32; }
    else if (pf >= 7340032)  { bg = 4; zc = 16; }
    else                     { bg = 2; zc = 16; }
    int ecs = 1;
    for (int c = 8; c >= 1; c >>= 1)
        if ((size_t)c * 4063232ull <= pf) { ecs = c; break; }
    int elog = (ecs == 8) ? 3 : (ecs == 4) ? 2 : (ecs == 2) ? 1 : 0;

    float* qreg = pool;
    float* vreg = qreg + (size_t)bg * 786432;
    float* sreg = vreg + (size_t)bg * 262144;

    h16* tlnh = (h16*)tln;
    h16* ctxh = (h16*)ctx;

    // ================= self attention =================
    ln_f16<<<NTOK, 256, 0, stream>>>(tgt, ln1w, ln1b, tlnh);

    for (int g0 = 0; g0 < BATCH; g0 += bg) {
        h16* sb = (h16*)sreg;
        h16* wf = sb;                               // self_in_w f16: 3,145,728 f16
        cvt_f16<<<1536, 256, 0, stream>>>(self_in_w, wf, 393216);

        h16* qkvh = (h16*)qreg;
        gemm_f16<<<dim3(24, bg * 4, 1), 256, 0, stream>>>(
            tlnh + (size_t)g0 * 524288, 1024, wf, 1024, self_in_b, qkvh, 1024, 3072);

        h16* vth = (h16*)vreg;
        vt_split<<<dim3(8, 1, bg * 16), 256, 0, stream>>>(qkvh + 2048, 3072, vth);

        h16* sh = sb;
        for (int c0 = 0; c0 < bg * 16; c0 += zc) {
            attn_qk<true><<<dim3(4, 4, zc), 256, 0, stream>>>(
                qkvh, 3072, qkvh + 1024, 3072, sh, c0);
            attn_pv<true><<<dim3(8, 1, zc), 512, 0, stream>>>(
                sh, vth + (size_t)c0 * 32768, ctxh, g0 * 16 + c0);
        }
    }
    {
        h16* sb = (h16*)sreg;
        h16* owhi = sb, *owlo = sb + 1048576;
        split_f16<<<512, 256, 0, stream>>>(self_out_w, owhi, owlo, 131072);
        gemm_f16x2_nt<<<dim3(8, 32, 1), 256, 0, stream>>>(
            ctxh, 1024, owhi, owlo, 1024, self_out_b, tgt, out, 1024, 1024);
    }

    // ================= cross attention =================
    ln_f16<<<NTOK, 256, 0, stream>>>(out, ln2w, ln2b, tlnh);

    for (int g0 = 0; g0 < BATCH; g0 += bg) {
        h16* sb = (h16*)sreg;
        h16* sf = sb;                               // src f16: bg*524288 f16
        h16* ef = sb + (size_t)bg * 524288;         // enc_in_w f16: 3,145,728 f16
        cvt_f16<<<bg * 256, 256, 0, stream>>>(src + (size_t)g0 * 524288, sf, bg * 65536);
        cvt_f16<<<1536, 256, 0, stream>>>(enc_in_w, ef, 393216);

        h16* q2h  = (h16*)qreg;
        h16* kv2h = q2h + (size_t)bg * 524288;
        gemm_f16<<<dim3(8, bg * 4, 1), 256, 0, stream>>>(
            tlnh + (size_t)g0 * 524288, 1024, ef, 1024, enc_in_b, q2h, 1024, 1024);
        gemm_f16<<<dim3(16, bg * 4, 1), 256, 0, stream>>>(
            sf, 1024, ef + 1048576, 1024, enc_in_b + 1024, kv2h, 1024, 2048);

        h16* vth = (h16*)vreg;
        vt_split<<<dim3(8, 1, bg * 16), 256, 0, stream>>>(kv2h + 1024, 2048, vth);

        h16* sh = sb;
        for (int c0 = 0; c0 < bg * 16; c0 += zc) {
            attn_qk<false><<<dim3(4, 4, zc), 256, 0, stream>>>(
                q2h, 1024, kv2h, 2048, sh, c0);
            attn_pv<false><<<dim3(8, 1, zc), 512, 0, stream>>>(
                sh, vth + (size_t)c0 * 32768, ctxh, g0 * 16 + c0);
        }
    }
    {
        h16* sb = (h16*)sreg;
        h16* owhi = sb, *owlo = sb + 1048576;
        split_f16<<<512, 256, 0, stream>>>(enc_out_w, owhi, owlo, 131072);
        gemm_f16x2_nt<<<dim3(8, 32, 1), 256, 0, stream>>>(
            ctxh, 1024, owhi, owlo, 1024, enc_out_b, out, out, 1024, 1024);
    }

    // ================= MoE =================
    ln_router<<<1024, 256, 0, stream>>>(out, ln3w, ln3b, rw, rb, token_mask, tln,
                                        eidxA, gateA, validA, partA);
    scan_kernel<<<1, 256, 0, stream>>>(eidxA, validA, gateA, pcA, gkA, keepA, countsA);

    long long sHalf = 0;
    for (int e0 = 0; e0 < NEXP; e0 += ecs) {
        unsigned short* wt   = (unsigned short*)pool;
        unsigned short* hB   = (unsigned short*)(pool + (size_t)ecs * 2097152);
        unsigned short* bufB = (unsigned short*)(pool + (size_t)ecs * 3407872);
        unsigned short* obB  = bufB;                       // ob0 overlays bufB
        sHalf = (long long)ecs * 655360;

        tcvt_kernel<<<dim3(64, 16, ecs), 256, 0, stream>>>(
            w1 + (size_t)e0 * 4194304, wt, 1024, 4096);
        dispatch_bf16<<<NTOK, 256, 0, stream>>>(tln, eidxA, pcA, keepA, bufB, e0, ecs);
        gemm_bf16_moe<128, true, true, 1><<<ecs * 5 * 32, 256, 0, stream>>>(
            bufB, wt, b1 + (size_t)e0 * 4096, hB,
            1024, 655360LL, 4194304LL, 2621440LL, 4096LL, 4096,
            ecs - 1, elog, 5, 32, countsA, e0, 0LL);

        tcvt_kernel<<<dim3(16, 64, ecs), 256, 0, stream>>>(
            w2 + (size_t)e0 * 4194304, wt, 4096, 1024);
        gemm_bf16_moe<64, false, false, 2><<<ecs * 5 * 16 * 2, 256, 0, stream>>>(
            hB, wt, b2 + (size_t)e0 * 1024, obB,
            4096, 2621440LL, 4194304LL, 655360LL, 1024LL, 1024,
            ecs - 1, elog, 5, 16, countsA, e0, sHalf);

        combine_bf16<<<NTOK, 256, 0, stream>>>(obB, eidxA, pcA, gkA, out, e0, ecs, sHalf);
    }

    // ===== losses =====
    loss_kernel<<<1, 64, 0, stream>>>(partA, countsA, out + (size_t)NTOK * DMODEL);
}